// Round 3
// baseline (18437.343 us; speedup 1.0000x reference)
//
#include <hip/hip_runtime.h>
#include <cmath>

#define HH   128
#define G3   384
#define TT   512
#define BTOT 512
#define BB   2
#define NBLK (BTOT / BB)   // 256 blocks = 1/CU
#define NTHR 512           // 8 waves, 2/SIMD
#define WT   32            // t-window staged in LDS

__device__ __forceinline__ float sigmoidf_(float x) {
    return 1.0f / (1.0f + __expf(-x));
}

// Thread map: kt = tid&3 owns a 32-wide K slice; gt = tid>>2 owns hidden unit j=gt,
// i.e. Whh/Wih rows {j, 128+j, 256+j}. After a 4-lane shfl reduce every lane holds the
// full (r,z,n) recurrent sums; lane kt=bb finalizes row b0+bb inline (no LDS staging).
// x-part: computed once per WT-step window into s_xi (3 gate passes, 32 wx regs each).
// h double-buffered in padded LDS -> 1 barrier/step, conflict-free ds_read_b128.
template <int INK, bool LAST>
__global__ __launch_bounds__(NTHR, 2) void gru_layer(
    const float* __restrict__ in, float* __restrict__ out,
    const float* __restrict__ Wih, const float* __restrict__ Whh,
    const float* __restrict__ bih, const float* __restrict__ bhh,
    const float* __restrict__ fcw, const float* __restrict__ fcb,
    float* __restrict__ fcout) {
    const int tid = threadIdx.x;
    const int kt  = tid & 3;
    const int gt  = tid >> 2;          // hidden unit j in [0,128)
    const int b0  = blockIdx.x * BB;

    // h slices padded to 36 floats: slice kt at byte kt*144 -> banks 4kt..4kt+3 (no conflict)
    __shared__ float s_h[2][BB][4][36];
    __shared__ float s_xi[BB][WT][G3];

    // ---- recurrent weights resident in VGPRs: rows {gt, 128+gt, 256+gt}, slice kt*32 ----
    float wh[3][32];
#pragma unroll
    for (int i = 0; i < 3; ++i) {
        const float* wr = Whh + ((size_t)(i * HH + gt)) * HH + kt * 32;
#pragma unroll
        for (int j = 0; j < 32; j += 4) {
            float4 v = *(const float4*)(wr + j);
            wh[i][j] = v.x; wh[i][j + 1] = v.y; wh[i][j + 2] = v.z; wh[i][j + 3] = v.w;
        }
    }
    float wx5[3][5];
    if (INK == 5) {
#pragma unroll
        for (int i = 0; i < 3; ++i)
#pragma unroll
            for (int j = 0; j < 5; ++j) wx5[i][j] = Wih[(i * HH + gt) * 5 + j];
    }

    const float br  = bih[gt] + bhh[gt];
    const float bz  = bih[HH + gt] + bhh[HH + gt];
    const float bxn = bih[2 * HH + gt];
    const float bhn = bhh[2 * HH + gt];

    if (tid < BB * HH) {
        int bb = tid >> 7, j = tid & (HH - 1);
        s_h[0][bb][j >> 5][j & 31] = 0.0f;
    }
    __syncthreads();

    for (int t0 = 0; t0 < TT; t0 += WT) {
        // ================= window x-GEMM into s_xi =================
        if (INK == 5) {
#pragma unroll 4
            for (int p = 0; p < BB * WT; ++p) {
                int bb = p >> 5, tw = p & (WT - 1);
                const float* ip = in + ((size_t)(b0 + bb) * TT + (t0 + tw)) * 5;
                float x0 = ip[0], x1 = ip[1], x2 = ip[2], x3 = ip[3], x4 = ip[4];
                float a0 = wx5[0][0]*x0 + wx5[0][1]*x1 + wx5[0][2]*x2 + wx5[0][3]*x3 + wx5[0][4]*x4;
                float a1 = wx5[1][0]*x0 + wx5[1][1]*x1 + wx5[1][2]*x2 + wx5[1][3]*x3 + wx5[1][4]*x4;
                float a2 = wx5[2][0]*x0 + wx5[2][1]*x1 + wx5[2][2]*x2 + wx5[2][3]*x3 + wx5[2][4]*x4;
                if (kt == (tw & 3)) {
                    s_xi[bb][tw][gt] = a0;
                    s_xi[bb][tw][HH + gt] = a1;
                    s_xi[bb][tw][2 * HH + gt] = a2;
                }
            }
        } else {
#pragma unroll 1   // keep gate passes sequential: wx live range = 32 regs, not 96
            for (int i = 0; i < 3; ++i) {
                float wx[32];
                const float* wr = Wih + ((size_t)(i * HH + gt)) * HH + kt * 32;
#pragma unroll
                for (int j = 0; j < 32; j += 4) {
                    float4 v = *(const float4*)(wr + j);
                    wx[j] = v.x; wx[j + 1] = v.y; wx[j + 2] = v.z; wx[j + 3] = v.w;
                }
#pragma unroll 4
                for (int p = 0; p < BB * WT; ++p) {
                    int bb = p >> 5, tw = p & (WT - 1);
                    const float* ip = in + ((size_t)(b0 + bb) * TT + (t0 + tw)) * HH + kt * 32;
                    float a = 0.f;
#pragma unroll
                    for (int jj = 0; jj < 32; jj += 4) {
                        float4 v = *(const float4*)(ip + jj);
                        a = fmaf(wx[jj], v.x, a);
                        a = fmaf(wx[jj + 1], v.y, a);
                        a = fmaf(wx[jj + 2], v.z, a);
                        a = fmaf(wx[jj + 3], v.w, a);
                    }
                    a += __shfl_xor(a, 1, 64);
                    a += __shfl_xor(a, 2, 64);
                    if (kt == (tw & 3)) s_xi[bb][tw][i * HH + gt] = a;
                }
            }
        }
        __syncthreads();   // s_xi ready for this window

        // ================= recurrent steps =================
        for (int tw = 0; tw < WT; ++tw) {
            const int t   = t0 + tw;
            const int cur = t & 1, nxt = cur ^ 1;

            float a00 = 0.f, a01 = 0.f, a02 = 0.f, a10 = 0.f, a11 = 0.f, a12 = 0.f;
            const float* hp0 = &s_h[cur][0][kt][0];
            const float* hp1 = &s_h[cur][1][kt][0];
#pragma unroll
            for (int jj = 0; jj < 32; jj += 4) {
                float4 u = *(const float4*)(hp0 + jj);
                float4 v = *(const float4*)(hp1 + jj);
                a00 = fmaf(wh[0][jj], u.x, a00); a00 = fmaf(wh[0][jj+1], u.y, a00);
                a00 = fmaf(wh[0][jj+2], u.z, a00); a00 = fmaf(wh[0][jj+3], u.w, a00);
                a01 = fmaf(wh[1][jj], u.x, a01); a01 = fmaf(wh[1][jj+1], u.y, a01);
                a01 = fmaf(wh[1][jj+2], u.z, a01); a01 = fmaf(wh[1][jj+3], u.w, a01);
                a02 = fmaf(wh[2][jj], u.x, a02); a02 = fmaf(wh[2][jj+1], u.y, a02);
                a02 = fmaf(wh[2][jj+2], u.z, a02); a02 = fmaf(wh[2][jj+3], u.w, a02);
                a10 = fmaf(wh[0][jj], v.x, a10); a10 = fmaf(wh[0][jj+1], v.y, a10);
                a10 = fmaf(wh[0][jj+2], v.z, a10); a10 = fmaf(wh[0][jj+3], v.w, a10);
                a11 = fmaf(wh[1][jj], v.x, a11); a11 = fmaf(wh[1][jj+1], v.y, a11);
                a11 = fmaf(wh[1][jj+2], v.z, a11); a11 = fmaf(wh[1][jj+3], v.w, a11);
                a12 = fmaf(wh[2][jj], v.x, a12); a12 = fmaf(wh[2][jj+1], v.y, a12);
                a12 = fmaf(wh[2][jj+2], v.z, a12); a12 = fmaf(wh[2][jj+3], v.w, a12);
            }
            a00 += __shfl_xor(a00, 1, 64); a00 += __shfl_xor(a00, 2, 64);
            a01 += __shfl_xor(a01, 1, 64); a01 += __shfl_xor(a01, 2, 64);
            a02 += __shfl_xor(a02, 1, 64); a02 += __shfl_xor(a02, 2, 64);
            a10 += __shfl_xor(a10, 1, 64); a10 += __shfl_xor(a10, 2, 64);
            a11 += __shfl_xor(a11, 1, 64); a11 += __shfl_xor(a11, 2, 64);
            a12 += __shfl_xor(a12, 1, 64); a12 += __shfl_xor(a12, 2, 64);

            // finalize: lane kt==bb owns row b0+bb (writes go to the OTHER h buffer,
            // so no barrier needed between reads above and these writes)
            if (kt < 2) {
                const int bb = kt;
                float g0 = (kt == 0) ? a00 : a10;
                float g1 = (kt == 0) ? a01 : a11;
                float g2 = (kt == 0) ? a02 : a12;
                float xr = s_xi[bb][tw][gt];
                float xz = s_xi[bb][tw][HH + gt];
                float xn = s_xi[bb][tw][2 * HH + gt];
                float r = sigmoidf_(xr + g0 + br);
                float z = sigmoidf_(xz + g1 + bz);
                float n = tanhf(xn + bxn + r * (g2 + bhn));
                float hp = s_h[cur][bb][gt >> 5][gt & 31];
                float hv = (1.0f - z) * n + z * hp;
                s_h[nxt][bb][gt >> 5][gt & 31] = hv;
                if (!LAST) out[((size_t)(b0 + bb) * TT + t) * HH + gt] = hv;
            }
            __syncthreads();   // the single per-step barrier: new h visible to all
        }
    }

    if (LAST) {
        // fused FC: out[b] = dot(h_last, fc_w) + fc_b ; final h is in buffer (TT&1)=0
        if (tid < 128) {
            int bb = tid >> 6, l = tid & 63, l2 = l + 64;
            float h0 = s_h[0][bb][l >> 5][l & 31];
            float h1 = s_h[0][bb][l2 >> 5][l2 & 31];
            float s = h0 * fcw[l] + h1 * fcw[l2];
#pragma unroll
            for (int m = 32; m >= 1; m >>= 1) s += __shfl_xor(s, m, 64);
            if (l == 0) fcout[b0 + bb] = s + fcb[0];
        }
    }
}

extern "C" void kernel_launch(void* const* d_in, const int* in_sizes, int n_in,
                              void* d_out, int out_size, void* d_ws, size_t ws_size,
                              hipStream_t stream) {
    const float* x    = (const float*)d_in[0];
    const float* Wih0 = (const float*)d_in[1];
    const float* Whh0 = (const float*)d_in[2];
    const float* bih0 = (const float*)d_in[3];
    const float* bhh0 = (const float*)d_in[4];
    const float* WihR = (const float*)d_in[5];
    const float* WhhR = (const float*)d_in[6];
    const float* bihR = (const float*)d_in[7];
    const float* bhhR = (const float*)d_in[8];
    const float* fcw  = (const float*)d_in[9];
    const float* fcb  = (const float*)d_in[10];

    float* buf = (float*)d_ws;   // 512*512*128*4 = 134 MB, in-place across layers

    gru_layer<5, false><<<NBLK, NTHR, 0, stream>>>(x, buf, Wih0, Whh0, bih0, bhh0,
                                                   nullptr, nullptr, nullptr);
    gru_layer<128, false><<<NBLK, NTHR, 0, stream>>>(buf, buf, WihR, WhhR, bihR, bhhR,
                                                     nullptr, nullptr, nullptr);
    gru_layer<128, false><<<NBLK, NTHR, 0, stream>>>(buf, buf, WihR + G3 * HH, WhhR + G3 * HH,
                                                     bihR + G3, bhhR + G3,
                                                     nullptr, nullptr, nullptr);
    gru_layer<128, true><<<NBLK, NTHR, 0, stream>>>(buf, buf, WihR + 2 * G3 * HH,
                                                    WhhR + 2 * G3 * HH, bihR + 2 * G3,
                                                    bhhR + 2 * G3, fcw, fcb, (float*)d_out);
}

// Round 4
// 3640.607 us; speedup vs baseline: 5.0644x; 5.0644x over previous
//
#include <hip/hip_runtime.h>
#include <cmath>

#define HH   128
#define G3   384
#define TT   512
#define BTOT 512
#define BB   2
#define NBLK (BTOT / BB)   // 256 blocks = 1 per CU
#define NTHR 512           // 8 waves, 2/SIMD, VGPR cap 256

__device__ __forceinline__ float sigmoidf_(float x) {
    return 1.0f / (1.0f + __expf(-x));
}

// Thread map: kt = tid&3 owns a 32-wide K slice, gt = tid>>2 owns hidden unit j
// (rows {j, 128+j, 256+j} of both weight matrices). Weights are loaded once and
// PINNED into VGPRs with empty asm (defeats the remat/sinking that caused round
// 2/3's per-step L2 weight streaming). h and x_t live in bank-padded LDS,
// double-buffered -> exactly 1 barrier per step. x_{t+1} is staged with a
// load-early/write-late split so HBM latency hides under the FMA burst.
template <int INK, bool LAST>
__global__ __launch_bounds__(NTHR, 2) void gru_layer(
    const float* in, float* out,   // may alias (in-place) -> NO __restrict__
    const float* __restrict__ Wih, const float* __restrict__ Whh,
    const float* __restrict__ bih, const float* __restrict__ bhh,
    const float* __restrict__ fcw, const float* __restrict__ fcb,
    float* __restrict__ fcout) {
    const int tid = threadIdx.x;
    const int kt  = tid & 3;
    const int gt  = tid >> 2;          // hidden unit j in [0,128)
    const int b0  = blockIdx.x * BB;

    // slice kt at float offset kt*36 -> bank quads {0-3},{4-7},{8-11},{12-15}: disjoint
    __shared__ __align__(16) float s_h[2][BB][4][36];
    __shared__ __align__(16) float s_x[2][BB][(INK == 5) ? 8 : 144];

    // ---- load + PIN recurrent weights: rows {gt,128+gt,256+gt}, slice kt*32 ----
    float wh[3][32];
#pragma unroll
    for (int i = 0; i < 3; ++i) {
        const float* wr = Whh + (size_t)(i * HH + gt) * HH + kt * 32;
#pragma unroll
        for (int j = 0; j < 32; j += 4) {
            float4 v = *(const float4*)(wr + j);
            wh[i][j] = v.x; wh[i][j + 1] = v.y; wh[i][j + 2] = v.z; wh[i][j + 3] = v.w;
        }
    }
#pragma unroll
    for (int i = 0; i < 3; ++i)
#pragma unroll
        for (int j = 0; j < 32; ++j) asm volatile("" : "+v"(wh[i][j]));

    float wx[3][32];   // INK==128 only
    float wx5[3][5];   // INK==5 only
    if constexpr (INK == 128) {
#pragma unroll
        for (int i = 0; i < 3; ++i) {
            const float* wr = Wih + (size_t)(i * HH + gt) * HH + kt * 32;
#pragma unroll
            for (int j = 0; j < 32; j += 4) {
                float4 v = *(const float4*)(wr + j);
                wx[i][j] = v.x; wx[i][j + 1] = v.y; wx[i][j + 2] = v.z; wx[i][j + 3] = v.w;
            }
        }
#pragma unroll
        for (int i = 0; i < 3; ++i)
#pragma unroll
            for (int j = 0; j < 32; ++j) asm volatile("" : "+v"(wx[i][j]));
    } else {
#pragma unroll
        for (int i = 0; i < 3; ++i)
#pragma unroll
            for (int j = 0; j < 5; ++j) wx5[i][j] = Wih[(i * HH + gt) * 5 + j];
#pragma unroll
        for (int i = 0; i < 3; ++i)
#pragma unroll
            for (int j = 0; j < 5; ++j) asm volatile("" : "+v"(wx5[i][j]));
    }

    const float br  = bih[gt] + bhh[gt];
    const float bz  = bih[HH + gt] + bhh[HH + gt];
    const float bxn = bih[2 * HH + gt];
    const float bhn = bhh[2 * HH + gt];

    // ---- init h = 0; stage x_0 into s_x[0] ----
    if (tid < BB * HH) {
        int bb = tid >> 7, j = tid & (HH - 1);
        s_h[0][bb][j >> 5][j & 31] = 0.0f;
    }
    if constexpr (INK == 5) {
        if (tid < BB * 5) {
            int bb = tid / 5, k = tid % 5;
            s_x[0][bb][k] = in[((size_t)(b0 + bb) * TT + 0) * 5 + k];
        }
    } else {
        if (tid < 64) {
            int row = tid >> 5, f = (tid & 31) * 4;
            float4 v = *(const float4*)&in[((size_t)(b0 + row) * TT + 0) * HH + f];
            *(float4*)&s_x[0][row][(f >> 5) * 36 + (f & 31)] = v;
        }
    }
    __syncthreads();

    for (int t = 0; t < TT; ++t) {
        const int cur = t & 1, nxt = cur ^ 1;

        // ---- stage load for x_{t+1}: ISSUE EARLY, write to LDS late ----
        float4 xs4 = make_float4(0.f, 0.f, 0.f, 0.f);
        float  xs1 = 0.f;
        if constexpr (INK == 5) {
            if (tid < BB * 5 && t + 1 < TT) {
                int bb = tid / 5, k = tid % 5;
                xs1 = in[((size_t)(b0 + bb) * TT + (t + 1)) * 5 + k];
            }
        } else {
            if (tid < 64 && t + 1 < TT) {
                int row = tid >> 5, f = (tid & 31) * 4;
                xs4 = *(const float4*)&in[((size_t)(b0 + row) * TT + (t + 1)) * HH + f];
            }
        }

        // ---- FMA burst: acc[bb] = {cr(x+h), cz(x+h), nx, nh} ----
        float acc[BB][4];
#pragma unroll
        for (int bb = 0; bb < BB; ++bb) {
            acc[bb][0] = 0.f; acc[bb][1] = 0.f; acc[bb][2] = 0.f; acc[bb][3] = 0.f;
        }
#pragma unroll
        for (int bb = 0; bb < BB; ++bb) {
            const float* hp = &s_h[cur][bb][kt][0];
            const float* xp = &s_x[cur][bb][(INK == 5) ? 0 : kt * 36];
#pragma unroll
            for (int jj = 0; jj < 32; jj += 4) {
                float4 hu = *(const float4*)(hp + jj);
                acc[bb][0] = fmaf(wh[0][jj], hu.x, acc[bb][0]);
                acc[bb][0] = fmaf(wh[0][jj+1], hu.y, acc[bb][0]);
                acc[bb][0] = fmaf(wh[0][jj+2], hu.z, acc[bb][0]);
                acc[bb][0] = fmaf(wh[0][jj+3], hu.w, acc[bb][0]);
                acc[bb][1] = fmaf(wh[1][jj], hu.x, acc[bb][1]);
                acc[bb][1] = fmaf(wh[1][jj+1], hu.y, acc[bb][1]);
                acc[bb][1] = fmaf(wh[1][jj+2], hu.z, acc[bb][1]);
                acc[bb][1] = fmaf(wh[1][jj+3], hu.w, acc[bb][1]);
                acc[bb][3] = fmaf(wh[2][jj], hu.x, acc[bb][3]);
                acc[bb][3] = fmaf(wh[2][jj+1], hu.y, acc[bb][3]);
                acc[bb][3] = fmaf(wh[2][jj+2], hu.z, acc[bb][3]);
                acc[bb][3] = fmaf(wh[2][jj+3], hu.w, acc[bb][3]);
                if constexpr (INK == 128) {
                    float4 xu = *(const float4*)(xp + jj);
                    acc[bb][0] = fmaf(wx[0][jj], xu.x, acc[bb][0]);
                    acc[bb][0] = fmaf(wx[0][jj+1], xu.y, acc[bb][0]);
                    acc[bb][0] = fmaf(wx[0][jj+2], xu.z, acc[bb][0]);
                    acc[bb][0] = fmaf(wx[0][jj+3], xu.w, acc[bb][0]);
                    acc[bb][1] = fmaf(wx[1][jj], xu.x, acc[bb][1]);
                    acc[bb][1] = fmaf(wx[1][jj+1], xu.y, acc[bb][1]);
                    acc[bb][1] = fmaf(wx[1][jj+2], xu.z, acc[bb][1]);
                    acc[bb][1] = fmaf(wx[1][jj+3], xu.w, acc[bb][1]);
                    acc[bb][2] = fmaf(wx[2][jj], xu.x, acc[bb][2]);
                    acc[bb][2] = fmaf(wx[2][jj+1], xu.y, acc[bb][2]);
                    acc[bb][2] = fmaf(wx[2][jj+2], xu.z, acc[bb][2]);
                    acc[bb][2] = fmaf(wx[2][jj+3], xu.w, acc[bb][2]);
                }
            }
        }
        // ---- 4-lane k-reduction (lanes differ in bits 0..1) ----
#pragma unroll
        for (int bb = 0; bb < BB; ++bb)
#pragma unroll
            for (int g = 0; g < 4; ++g) {
                if (INK == 5 && g == 2) continue;   // no sliced x-part for K=5
                acc[bb][g] += __shfl_xor(acc[bb][g], 1, 64);
                acc[bb][g] += __shfl_xor(acc[bb][g], 2, 64);
            }

        // ---- finalize on lanes kt<2 (bb = kt); writes go to the OTHER h buffer ----
        if (kt < 2) {
            const int bb = kt;
            float cr  = (kt == 0) ? acc[0][0] : acc[1][0];
            float cz  = (kt == 0) ? acc[0][1] : acc[1][1];
            float cnx = (kt == 0) ? acc[0][2] : acc[1][2];
            float cnh = (kt == 0) ? acc[0][3] : acc[1][3];
            if constexpr (INK == 5) {
                float x0 = s_x[cur][bb][0], x1 = s_x[cur][bb][1], x2 = s_x[cur][bb][2];
                float x3 = s_x[cur][bb][3], x4 = s_x[cur][bb][4];
                cr += wx5[0][0]*x0 + wx5[0][1]*x1 + wx5[0][2]*x2 + wx5[0][3]*x3 + wx5[0][4]*x4;
                cz += wx5[1][0]*x0 + wx5[1][1]*x1 + wx5[1][2]*x2 + wx5[1][3]*x3 + wx5[1][4]*x4;
                cnx = wx5[2][0]*x0 + wx5[2][1]*x1 + wx5[2][2]*x2 + wx5[2][3]*x3 + wx5[2][4]*x4;
            }
            float r = sigmoidf_(cr + br);
            float z = sigmoidf_(cz + bz);
            float n = tanhf(cnx + bxn + r * (cnh + bhn));
            float hp = s_h[cur][bb][gt >> 5][gt & 31];
            float hv = (1.0f - z) * n + z * hp;
            s_h[nxt][bb][gt >> 5][gt & 31] = hv;
            if (!LAST) out[((size_t)(b0 + bb) * TT + t) * HH + gt] = hv;
        }

        // ---- stage write for x_{t+1} (latency hidden under the FMA burst) ----
        if constexpr (INK == 5) {
            if (tid < BB * 5 && t + 1 < TT) {
                int bb = tid / 5, k = tid % 5;
                s_x[nxt][bb][k] = xs1;
            }
        } else {
            if (tid < 64 && t + 1 < TT) {
                int row = tid >> 5, f = (tid & 31) * 4;
                *(float4*)&s_x[nxt][row][(f >> 5) * 36 + (f & 31)] = xs4;
            }
        }
        __syncthreads();   // single per-step barrier
    }

    if (LAST) {
        // fused FC: final h is in s_h[0] (nxt of t=511 is 0); wave0->b0, wave1->b0+1
        if (tid < 128) {
            int bb = tid >> 6, l = tid & 63;
            float h0 = s_h[0][bb][l >> 5][l & 31];
            float h1 = s_h[0][bb][(l >> 5) + 2][l & 31];
            float s = h0 * fcw[l] + h1 * fcw[l + 64];
#pragma unroll
            for (int m = 32; m >= 1; m >>= 1) s += __shfl_xor(s, m, 64);
            if (l == 0) fcout[b0 + bb] = s + fcb[0];
        }
    }
}

extern "C" void kernel_launch(void* const* d_in, const int* in_sizes, int n_in,
                              void* d_out, int out_size, void* d_ws, size_t ws_size,
                              hipStream_t stream) {
    const float* x    = (const float*)d_in[0];
    const float* Wih0 = (const float*)d_in[1];
    const float* Whh0 = (const float*)d_in[2];
    const float* bih0 = (const float*)d_in[3];
    const float* bhh0 = (const float*)d_in[4];
    const float* WihR = (const float*)d_in[5];
    const float* WhhR = (const float*)d_in[6];
    const float* bihR = (const float*)d_in[7];
    const float* bhhR = (const float*)d_in[8];
    const float* fcw  = (const float*)d_in[9];
    const float* fcb  = (const float*)d_in[10];

    float* buf = (float*)d_ws;   // 512*512*128*4 = 134 MB, in-place across layers

    gru_layer<5, false><<<NBLK, NTHR, 0, stream>>>(x, buf, Wih0, Whh0, bih0, bhh0,
                                                   nullptr, nullptr, nullptr);
    gru_layer<128, false><<<NBLK, NTHR, 0, stream>>>(buf, buf, WihR, WhhR, bihR, bhhR,
                                                     nullptr, nullptr, nullptr);
    gru_layer<128, false><<<NBLK, NTHR, 0, stream>>>(buf, buf, WihR + G3 * HH, WhhR + G3 * HH,
                                                     bihR + G3, bhhR + G3,
                                                     nullptr, nullptr, nullptr);
    gru_layer<128, true><<<NBLK, NTHR, 0, stream>>>(buf, buf, WihR + 2 * G3 * HH,
                                                    WhhR + 2 * G3 * HH, bihR + 2 * G3,
                                                    bhhR + 2 * G3, fcw, fcb, (float*)d_out);
}

// Round 5
// 3312.442 us; speedup vs baseline: 5.5661x; 1.0991x over previous
//
#include <hip/hip_runtime.h>
#include <cmath>

#define HH   128
#define G3   384
#define TT   512
#define BTOT 512
#define BB   2
#define NBLK (BTOT / BB)   // 256 blocks = 1 per CU
#define NTHR 512           // 8 waves, 2/SIMD

__device__ __forceinline__ float sigmoidf_(float x) {
    return 1.0f / (1.0f + __expf(-x));
}
__device__ __forceinline__ float tanhf_(float x) {
    float e = __expf(2.0f * x);
    return 1.0f - 2.0f / (e + 1.0f);   // exact at +-inf, ~ulp-level error elsewhere
}
// lgkmcnt(0)-only barrier: LDS writes visible, but vmem loads STAY IN FLIGHT
// (__syncthreads would drain vmcnt(0) and kill the depth-2 prefetch)
__device__ __forceinline__ void lds_barrier() {
    asm volatile("s_waitcnt lgkmcnt(0)" ::: "memory");
    __builtin_amdgcn_s_barrier();
}

// ============================================================================
// xi GEMM: xi[tok][g] = sum_k hin[tok][k] * Wih[g][k]   (tok = b*TT + t)
// block = 512 thr: g = tid&127, tq = tid>>7 -> 8 tokens each; tile 32 tokens.
// Weight rows are L1-resident (24 KB of 64B lines reused across k-chunks).
__global__ __launch_bounds__(512, 4) void xi_gemm(
    const float* __restrict__ hin, const float* __restrict__ Wih,
    float* __restrict__ xi) {
    const int tid = threadIdx.x;
    const int g   = tid & 127;
    const int tq  = tid >> 7;
    const size_t tok0 = (size_t)blockIdx.x * 32;
    __shared__ __align__(16) float s_in[32][HH];
#pragma unroll
    for (int r = 0; r < 2; ++r) {
        int f4 = tid * 2 + r;
        int tk = f4 >> 5, k4 = (f4 & 31) << 2;
        *(float4*)&s_in[tk][k4] = *(const float4*)&hin[(tok0 + tk) * HH + k4];
    }
    __syncthreads();
    float acc[3][8];
#pragma unroll
    for (int i = 0; i < 3; ++i)
#pragma unroll
        for (int t = 0; t < 8; ++t) acc[i][t] = 0.0f;
    const float* w0 = Wih + (size_t)g * HH;
    const float* w1 = Wih + (size_t)(HH + g) * HH;
    const float* w2 = Wih + (size_t)(2 * HH + g) * HH;
#pragma unroll 2
    for (int kc = 0; kc < 32; ++kc) {
        float4 wa = *(const float4*)(w0 + kc * 4);
        float4 wb = *(const float4*)(w1 + kc * 4);
        float4 wc = *(const float4*)(w2 + kc * 4);
#pragma unroll
        for (int t = 0; t < 8; ++t) {
            float4 sv = *(const float4*)&s_in[tq * 8 + t][kc * 4];
            acc[0][t] = fmaf(wa.x, sv.x, acc[0][t]); acc[0][t] = fmaf(wa.y, sv.y, acc[0][t]);
            acc[0][t] = fmaf(wa.z, sv.z, acc[0][t]); acc[0][t] = fmaf(wa.w, sv.w, acc[0][t]);
            acc[1][t] = fmaf(wb.x, sv.x, acc[1][t]); acc[1][t] = fmaf(wb.y, sv.y, acc[1][t]);
            acc[1][t] = fmaf(wb.z, sv.z, acc[1][t]); acc[1][t] = fmaf(wb.w, sv.w, acc[1][t]);
            acc[2][t] = fmaf(wc.x, sv.x, acc[2][t]); acc[2][t] = fmaf(wc.y, sv.y, acc[2][t]);
            acc[2][t] = fmaf(wc.z, sv.z, acc[2][t]); acc[2][t] = fmaf(wc.w, sv.w, acc[2][t]);
        }
    }
#pragma unroll
    for (int i = 0; i < 3; ++i)
#pragma unroll
        for (int t = 0; t < 8; ++t)
            xi[(tok0 + tq * 8 + t) * G3 + i * HH + g] = acc[i][t];
}

// ============================================================================
// Recurrent kernel: h-matvec only (x-part precomputed as xi, except layer 1's
// tiny K=5 dot which stays fused). kt=tid&3 owns a 32-k slice, gt=tid>>2 owns
// hidden unit j (Whh rows {j,128+j,256+j} pinned in VGPRs: 96 floats).
// xi prefetched depth-2 in regs; loads cross lds_barrier() in flight.
template <bool FIRST, bool LAST>
__global__ __launch_bounds__(NTHR, 2) void gru_rec(
    const float* __restrict__ xin,   // FIRST: x (B,T,5); else xi (B,T,384)
    float* __restrict__ hout,        // !LAST: h sequence (B,T,128)
    const float* __restrict__ Wih5, const float* __restrict__ Whh,
    const float* __restrict__ bih, const float* __restrict__ bhh,
    const float* __restrict__ fcw, const float* __restrict__ fcb,
    float* __restrict__ fcout) {
    const int tid = threadIdx.x;
    const int kt  = tid & 3;
    const int gt  = tid >> 2;
    const int b0  = blockIdx.x * BB;

    __shared__ __align__(16) float s_h[2][BB][4][36];   // padded: slice kt -> banks 4kt..4kt+3
    __shared__ __align__(16) float s_xi[2][BB][G3];
    __shared__ float s_x5[2][BB][8];

    float wh[3][32];
#pragma unroll
    for (int i = 0; i < 3; ++i) {
        const float* wr = Whh + (size_t)(i * HH + gt) * HH + kt * 32;
#pragma unroll
        for (int j = 0; j < 32; j += 4) {
            float4 v = *(const float4*)(wr + j);
            wh[i][j] = v.x; wh[i][j + 1] = v.y; wh[i][j + 2] = v.z; wh[i][j + 3] = v.w;
        }
    }
#pragma unroll
    for (int i = 0; i < 3; ++i)
#pragma unroll
        for (int j = 0; j < 32; ++j) asm volatile("" : "+v"(wh[i][j]));

    float wx5[3][5];
    if constexpr (FIRST) {
#pragma unroll
        for (int i = 0; i < 3; ++i)
#pragma unroll
            for (int j = 0; j < 5; ++j) wx5[i][j] = Wih5[(i * HH + gt) * 5 + j];
    }

    const float br  = bih[gt] + bhh[gt];
    const float bz  = bih[HH + gt] + bhh[HH + gt];
    const float bxn = bih[2 * HH + gt];
    const float bhn = bhh[2 * HH + gt];

    if (tid < BB * HH) {
        int bb = tid >> 7, j = tid & (HH - 1);
        s_h[0][bb][j >> 5][j & 31] = 0.0f;
    }

    // ---- prologue: s_xi[0] <- xi(0); P0 <- xi(1); P1 <- xi(2) ----
    float4 P0 = make_float4(0.f, 0.f, 0.f, 0.f), P1 = P0;
    float  q0 = 0.f, q1 = 0.f;
    if constexpr (!FIRST) {
        if (tid < 192) {
            int bb = tid / 96, e = tid % 96;
            const float* base = xin + ((size_t)(b0 + bb) * TT) * G3 + e * 4;
            float4 v = *(const float4*)(base);
            P0 = *(const float4*)(base + (size_t)G3);
            P1 = *(const float4*)(base + (size_t)2 * G3);
            *(float4*)&s_xi[0][bb][e * 4] = v;
        }
    } else {
        if (tid < 16) {
            int bb = tid >> 3, k = tid & 7;
            if (k < 5) {
                const float* base = xin + ((size_t)(b0 + bb) * TT) * 5 + k;
                float v = base[0];
                q0 = base[5];
                q1 = base[10];
                s_x5[0][bb][k] = v;
            }
        }
    }
    __syncthreads();   // one-time full drain is fine here

#define REC_STEP(CUR, T, PV, QV)                                                   \
    {                                                                              \
        /* stage xi(T+1) -> s_xi[CUR^1]; issue load of xi(T+3) into PV */          \
        if constexpr (!FIRST) {                                                    \
            if (tid < 192) {                                                       \
                int bb = tid / 96, e = tid % 96;                                   \
                *(float4*)&s_xi[CUR ^ 1][bb][e * 4] = PV;                          \
                int tl = (T) + 3 < TT ? (T) + 3 : TT - 1;                          \
                PV = *(const float4*)(xin + ((size_t)(b0 + bb) * TT + tl) * G3 + e * 4); \
            }                                                                      \
        } else {                                                                   \
            if (tid < 16) {                                                        \
                int bb = tid >> 3, k = tid & 7;                                    \
                if (k < 5) {                                                       \
                    s_x5[CUR ^ 1][bb][k] = QV;                                     \
                    int tl = (T) + 3 < TT ? (T) + 3 : TT - 1;                      \
                    QV = xin[((size_t)(b0 + bb) * TT + tl) * 5 + k];               \
                }                                                                  \
            }                                                                      \
        }                                                                          \
        float a00 = 0.f, a01 = 0.f, a02 = 0.f, a10 = 0.f, a11 = 0.f, a12 = 0.f;    \
        const float* hp0 = &s_h[CUR][0][kt][0];                                    \
        const float* hp1 = &s_h[CUR][1][kt][0];                                    \
        _Pragma("unroll")                                                          \
        for (int jj = 0; jj < 32; jj += 4) {                                       \
            float4 u = *(const float4*)(hp0 + jj);                                 \
            float4 v = *(const float4*)(hp1 + jj);                                 \
            a00 = fmaf(wh[0][jj], u.x, a00); a00 = fmaf(wh[0][jj+1], u.y, a00);    \
            a00 = fmaf(wh[0][jj+2], u.z, a00); a00 = fmaf(wh[0][jj+3], u.w, a00);  \
            a01 = fmaf(wh[1][jj], u.x, a01); a01 = fmaf(wh[1][jj+1], u.y, a01);    \
            a01 = fmaf(wh[1][jj+2], u.z, a01); a01 = fmaf(wh[1][jj+3], u.w, a01);  \
            a02 = fmaf(wh[2][jj], u.x, a02); a02 = fmaf(wh[2][jj+1], u.y, a02);    \
            a02 = fmaf(wh[2][jj+2], u.z, a02); a02 = fmaf(wh[2][jj+3], u.w, a02);  \
            a10 = fmaf(wh[0][jj], v.x, a10); a10 = fmaf(wh[0][jj+1], v.y, a10);    \
            a10 = fmaf(wh[0][jj+2], v.z, a10); a10 = fmaf(wh[0][jj+3], v.w, a10);  \
            a11 = fmaf(wh[1][jj], v.x, a11); a11 = fmaf(wh[1][jj+1], v.y, a11);    \
            a11 = fmaf(wh[1][jj+2], v.z, a11); a11 = fmaf(wh[1][jj+3], v.w, a11);  \
            a12 = fmaf(wh[2][jj], v.x, a12); a12 = fmaf(wh[2][jj+1], v.y, a12);    \
            a12 = fmaf(wh[2][jj+2], v.z, a12); a12 = fmaf(wh[2][jj+3], v.w, a12);  \
        }                                                                          \
        a00 += __shfl_xor(a00, 1, 64); a00 += __shfl_xor(a00, 2, 64);              \
        a01 += __shfl_xor(a01, 1, 64); a01 += __shfl_xor(a01, 2, 64);              \
        a02 += __shfl_xor(a02, 1, 64); a02 += __shfl_xor(a02, 2, 64);              \
        a10 += __shfl_xor(a10, 1, 64); a10 += __shfl_xor(a10, 2, 64);              \
        a11 += __shfl_xor(a11, 1, 64); a11 += __shfl_xor(a11, 2, 64);              \
        a12 += __shfl_xor(a12, 1, 64); a12 += __shfl_xor(a12, 2, 64);              \
        if (kt < 2) {                                                              \
            const int bb = kt;                                                     \
            float cr  = (kt == 0) ? a00 : a10;                                     \
            float cz  = (kt == 0) ? a01 : a11;                                     \
            float cnh = (kt == 0) ? a02 : a12;                                     \
            float xr, xz, xn;                                                      \
            if constexpr (!FIRST) {                                                \
                xr = s_xi[CUR][bb][gt];                                            \
                xz = s_xi[CUR][bb][HH + gt];                                       \
                xn = s_xi[CUR][bb][2 * HH + gt];                                   \
            } else {                                                               \
                float x0 = s_x5[CUR][bb][0], x1 = s_x5[CUR][bb][1];                \
                float x2 = s_x5[CUR][bb][2], x3 = s_x5[CUR][bb][3];                \
                float x4 = s_x5[CUR][bb][4];                                       \
                xr = wx5[0][0]*x0 + wx5[0][1]*x1 + wx5[0][2]*x2 + wx5[0][3]*x3 + wx5[0][4]*x4; \
                xz = wx5[1][0]*x0 + wx5[1][1]*x1 + wx5[1][2]*x2 + wx5[1][3]*x3 + wx5[1][4]*x4; \
                xn = wx5[2][0]*x0 + wx5[2][1]*x1 + wx5[2][2]*x2 + wx5[2][3]*x3 + wx5[2][4]*x4; \
            }                                                                      \
            float r = sigmoidf_(xr + cr + br);                                     \
            float z = sigmoidf_(xz + cz + bz);                                     \
            float n = tanhf_(xn + bxn + r * (cnh + bhn));                          \
            float hp = s_h[CUR][bb][gt >> 5][gt & 31];                             \
            float hv = (1.0f - z) * n + z * hp;                                    \
            s_h[CUR ^ 1][bb][gt >> 5][gt & 31] = hv;                               \
            if constexpr (!LAST)                                                   \
                hout[((size_t)(b0 + bb) * TT + (T)) * HH + gt] = hv;               \
        }                                                                          \
        lds_barrier();                                                             \
    }

#pragma unroll 1
    for (int t = 0; t < TT; t += 2) {
        REC_STEP(0, t, P0, q0)
        REC_STEP(1, t + 1, P1, q1)
    }
#undef REC_STEP

    if constexpr (LAST) {
        if (tid < 128) {
            int bb = tid >> 6, l = tid & 63;
            float h0 = s_h[0][bb][l >> 5][l & 31];
            float h1 = s_h[0][bb][(l >> 5) + 2][l & 31];
            float s = h0 * fcw[l] + h1 * fcw[l + 64];
#pragma unroll
            for (int m = 32; m >= 1; m >>= 1) s += __shfl_xor(s, m, 64);
            if (l == 0) fcout[b0 + bb] = s + fcb[0];
        }
    }
}

// ============================================================================
// FALLBACK (ws too small for xi): round-4 fused kernel, proven correct.
template <int INK, bool LAST>
__global__ __launch_bounds__(NTHR, 2) void gru_fused(
    const float* in, float* out,
    const float* __restrict__ Wih, const float* __restrict__ Whh,
    const float* __restrict__ bih, const float* __restrict__ bhh,
    const float* __restrict__ fcw, const float* __restrict__ fcb,
    float* __restrict__ fcout) {
    const int tid = threadIdx.x;
    const int kt  = tid & 3;
    const int gt  = tid >> 2;
    const int b0  = blockIdx.x * BB;
    __shared__ __align__(16) float s_h[2][BB][4][36];
    __shared__ __align__(16) float s_x[2][BB][(INK == 5) ? 8 : 144];
    float wh[3][32];
#pragma unroll
    for (int i = 0; i < 3; ++i) {
        const float* wr = Whh + (size_t)(i * HH + gt) * HH + kt * 32;
#pragma unroll
        for (int j = 0; j < 32; j += 4) {
            float4 v = *(const float4*)(wr + j);
            wh[i][j] = v.x; wh[i][j + 1] = v.y; wh[i][j + 2] = v.z; wh[i][j + 3] = v.w;
        }
    }
#pragma unroll
    for (int i = 0; i < 3; ++i)
#pragma unroll
        for (int j = 0; j < 32; ++j) asm volatile("" : "+v"(wh[i][j]));
    float wx[3][32]; float wx5[3][5];
    if constexpr (INK == 128) {
#pragma unroll
        for (int i = 0; i < 3; ++i) {
            const float* wr = Wih + (size_t)(i * HH + gt) * HH + kt * 32;
#pragma unroll
            for (int j = 0; j < 32; j += 4) {
                float4 v = *(const float4*)(wr + j);
                wx[i][j] = v.x; wx[i][j + 1] = v.y; wx[i][j + 2] = v.z; wx[i][j + 3] = v.w;
            }
        }
#pragma unroll
        for (int i = 0; i < 3; ++i)
#pragma unroll
            for (int j = 0; j < 32; ++j) asm volatile("" : "+v"(wx[i][j]));
    } else {
#pragma unroll
        for (int i = 0; i < 3; ++i)
#pragma unroll
            for (int j = 0; j < 5; ++j) wx5[i][j] = Wih[(i * HH + gt) * 5 + j];
    }
    const float br  = bih[gt] + bhh[gt];
    const float bz  = bih[HH + gt] + bhh[HH + gt];
    const float bxn = bih[2 * HH + gt];
    const float bhn = bhh[2 * HH + gt];
    if (tid < BB * HH) {
        int bb = tid >> 7, j = tid & (HH - 1);
        s_h[0][bb][j >> 5][j & 31] = 0.0f;
    }
    if constexpr (INK == 5) {
        if (tid < BB * 5) {
            int bb = tid / 5, k = tid % 5;
            s_x[0][bb][k] = in[((size_t)(b0 + bb) * TT) * 5 + k];
        }
    } else {
        if (tid < 64) {
            int row = tid >> 5, f = (tid & 31) * 4;
            float4 v = *(const float4*)&in[((size_t)(b0 + row) * TT) * HH + f];
            *(float4*)&s_x[0][row][(f >> 5) * 36 + (f & 31)] = v;
        }
    }
    __syncthreads();
    for (int t = 0; t < TT; ++t) {
        const int cur = t & 1, nxt = cur ^ 1;
        float4 xs4 = make_float4(0.f, 0.f, 0.f, 0.f);
        float  xs1 = 0.f;
        if constexpr (INK == 5) {
            if (tid < BB * 5 && t + 1 < TT) {
                int bb = tid / 5, k = tid % 5;
                xs1 = in[((size_t)(b0 + bb) * TT + (t + 1)) * 5 + k];
            }
        } else {
            if (tid < 64 && t + 1 < TT) {
                int row = tid >> 5, f = (tid & 31) * 4;
                xs4 = *(const float4*)&in[((size_t)(b0 + row) * TT + (t + 1)) * HH + f];
            }
        }
        float acc[BB][4];
#pragma unroll
        for (int bb = 0; bb < BB; ++bb) {
            acc[bb][0] = 0.f; acc[bb][1] = 0.f; acc[bb][2] = 0.f; acc[bb][3] = 0.f;
        }
#pragma unroll
        for (int bb = 0; bb < BB; ++bb) {
            const float* hp = &s_h[cur][bb][kt][0];
            const float* xp = &s_x[cur][bb][(INK == 5) ? 0 : kt * 36];
#pragma unroll
            for (int jj = 0; jj < 32; jj += 4) {
                float4 hu = *(const float4*)(hp + jj);
                acc[bb][0] = fmaf(wh[0][jj], hu.x, acc[bb][0]);
                acc[bb][0] = fmaf(wh[0][jj+1], hu.y, acc[bb][0]);
                acc[bb][0] = fmaf(wh[0][jj+2], hu.z, acc[bb][0]);
                acc[bb][0] = fmaf(wh[0][jj+3], hu.w, acc[bb][0]);
                acc[bb][1] = fmaf(wh[1][jj], hu.x, acc[bb][1]);
                acc[bb][1] = fmaf(wh[1][jj+1], hu.y, acc[bb][1]);
                acc[bb][1] = fmaf(wh[1][jj+2], hu.z, acc[bb][1]);
                acc[bb][1] = fmaf(wh[1][jj+3], hu.w, acc[bb][1]);
                acc[bb][3] = fmaf(wh[2][jj], hu.x, acc[bb][3]);
                acc[bb][3] = fmaf(wh[2][jj+1], hu.y, acc[bb][3]);
                acc[bb][3] = fmaf(wh[2][jj+2], hu.z, acc[bb][3]);
                acc[bb][3] = fmaf(wh[2][jj+3], hu.w, acc[bb][3]);
                if constexpr (INK == 128) {
                    float4 xu = *(const float4*)(xp + jj);
                    acc[bb][0] = fmaf(wx[0][jj], xu.x, acc[bb][0]);
                    acc[bb][0] = fmaf(wx[0][jj+1], xu.y, acc[bb][0]);
                    acc[bb][0] = fmaf(wx[0][jj+2], xu.z, acc[bb][0]);
                    acc[bb][0] = fmaf(wx[0][jj+3], xu.w, acc[bb][0]);
                    acc[bb][1] = fmaf(wx[1][jj], xu.x, acc[bb][1]);
                    acc[bb][1] = fmaf(wx[1][jj+1], xu.y, acc[bb][1]);
                    acc[bb][1] = fmaf(wx[1][jj+2], xu.z, acc[bb][1]);
                    acc[bb][1] = fmaf(wx[1][jj+3], xu.w, acc[bb][1]);
                    acc[bb][2] = fmaf(wx[2][jj], xu.x, acc[bb][2]);
                    acc[bb][2] = fmaf(wx[2][jj+1], xu.y, acc[bb][2]);
                    acc[bb][2] = fmaf(wx[2][jj+2], xu.z, acc[bb][2]);
                    acc[bb][2] = fmaf(wx[2][jj+3], xu.w, acc[bb][2]);
                }
            }
        }
#pragma unroll
        for (int bb = 0; bb < BB; ++bb)
#pragma unroll
            for (int g = 0; g < 4; ++g) {
                if (INK == 5 && g == 2) continue;
                acc[bb][g] += __shfl_xor(acc[bb][g], 1, 64);
                acc[bb][g] += __shfl_xor(acc[bb][g], 2, 64);
            }
        if (kt < 2) {
            const int bb = kt;
            float cr  = (kt == 0) ? acc[0][0] : acc[1][0];
            float cz  = (kt == 0) ? acc[0][1] : acc[1][1];
            float cnx = (kt == 0) ? acc[0][2] : acc[1][2];
            float cnh = (kt == 0) ? acc[0][3] : acc[1][3];
            if constexpr (INK == 5) {
                float x0 = s_x[cur][bb][0], x1 = s_x[cur][bb][1], x2 = s_x[cur][bb][2];
                float x3 = s_x[cur][bb][3], x4 = s_x[cur][bb][4];
                cr += wx5[0][0]*x0 + wx5[0][1]*x1 + wx5[0][2]*x2 + wx5[0][3]*x3 + wx5[0][4]*x4;
                cz += wx5[1][0]*x0 + wx5[1][1]*x1 + wx5[1][2]*x2 + wx5[1][3]*x3 + wx5[1][4]*x4;
                cnx = wx5[2][0]*x0 + wx5[2][1]*x1 + wx5[2][2]*x2 + wx5[2][3]*x3 + wx5[2][4]*x4;
            }
            float r = sigmoidf_(cr + br);
            float z = sigmoidf_(cz + bz);
            float n = tanhf_(cnx + bxn + r * (cnh + bhn));
            float hp = s_h[cur][bb][gt >> 5][gt & 31];
            float hv = (1.0f - z) * n + z * hp;
            s_h[nxt][bb][gt >> 5][gt & 31] = hv;
            if (!LAST) out[((size_t)(b0 + bb) * TT + t) * HH + gt] = hv;
        }
        if constexpr (INK == 5) {
            if (tid < BB * 5 && t + 1 < TT) {
                int bb = tid / 5, k = tid % 5;
                s_x[nxt][bb][k] = xs1;
            }
        } else {
            if (tid < 64 && t + 1 < TT) {
                int row = tid >> 5, f = (tid & 31) * 4;
                *(float4*)&s_x[nxt][row][(f >> 5) * 36 + (f & 31)] = xs4;
            }
        }
        __syncthreads();
    }
    if (LAST) {
        if (tid < 128) {
            int bb = tid >> 6, l = tid & 63;
            float h0 = s_h[0][bb][l >> 5][l & 31];
            float h1 = s_h[0][bb][(l >> 5) + 2][l & 31];
            float s = h0 * fcw[l] + h1 * fcw[l + 64];
#pragma unroll
            for (int m = 32; m >= 1; m >>= 1) s += __shfl_xor(s, m, 64);
            if (l == 0) fcout[b0 + bb] = s + fcb[0];
        }
    }
}

extern "C" void kernel_launch(void* const* d_in, const int* in_sizes, int n_in,
                              void* d_out, int out_size, void* d_ws, size_t ws_size,
                              hipStream_t stream) {
    const float* x    = (const float*)d_in[0];
    const float* Wih0 = (const float*)d_in[1];
    const float* Whh0 = (const float*)d_in[2];
    const float* bih0 = (const float*)d_in[3];
    const float* bhh0 = (const float*)d_in[4];
    const float* WihR = (const float*)d_in[5];
    const float* WhhR = (const float*)d_in[6];
    const float* bihR = (const float*)d_in[7];
    const float* bhhR = (const float*)d_in[8];
    const float* fcw  = (const float*)d_in[9];
    const float* fcb  = (const float*)d_in[10];

    const size_t BUF_B = (size_t)BTOT * TT * HH * 4;   // 134,217,728
    const size_t XI_B  = (size_t)BTOT * TT * G3 * 4;   // 402,653,184
    float* buf = (float*)d_ws;

    if (ws_size >= BUF_B + XI_B) {
        float* xi = (float*)((char*)d_ws + BUF_B);
        const int GB = (BTOT * TT) / 32;   // 8192 GEMM blocks
        gru_rec<true, false><<<NBLK, NTHR, 0, stream>>>(x, buf, Wih0, Whh0, bih0, bhh0,
                                                        nullptr, nullptr, nullptr);
        for (int l = 0; l < 3; ++l) {
            xi_gemm<<<GB, 512, 0, stream>>>(buf, WihR + (size_t)l * G3 * HH, xi);
            if (l < 2)
                gru_rec<false, false><<<NBLK, NTHR, 0, stream>>>(
                    xi, buf, nullptr, WhhR + (size_t)l * G3 * HH, bihR + l * G3,
                    bhhR + l * G3, nullptr, nullptr, nullptr);
            else
                gru_rec<false, true><<<NBLK, NTHR, 0, stream>>>(
                    xi, buf, nullptr, WhhR + (size_t)l * G3 * HH, bihR + l * G3,
                    bhhR + l * G3, fcw, fcb, (float*)d_out);
        }
    } else {
        gru_fused<5, false><<<NBLK, NTHR, 0, stream>>>(x, buf, Wih0, Whh0, bih0, bhh0,
                                                       nullptr, nullptr, nullptr);
        gru_fused<128, false><<<NBLK, NTHR, 0, stream>>>(buf, buf, WihR, WhhR, bihR, bhhR,
                                                         nullptr, nullptr, nullptr);
        gru_fused<128, false><<<NBLK, NTHR, 0, stream>>>(buf, buf, WihR + G3 * HH,
                                                         WhhR + G3 * HH, bihR + G3,
                                                         bhhR + G3, nullptr, nullptr, nullptr);
        gru_fused<128, true><<<NBLK, NTHR, 0, stream>>>(buf, buf, WihR + 2 * G3 * HH,
                                                        WhhR + 2 * G3 * HH, bihR + 2 * G3,
                                                        bhhR + 2 * G3, fcw, fcb, (float*)d_out);
    }
}

// Round 6
// 3312.370 us; speedup vs baseline: 5.5662x; 1.0000x over previous
//
#include <hip/hip_runtime.h>
#include <cmath>

#define HH   128
#define G3   384
#define TT   512
#define BTOT 512
#define BB   2
#define NBLK (BTOT / BB)   // 256 blocks = 1 per CU
#define NTHR 512           // 8 waves, 2/SIMD

__device__ __forceinline__ float sigmoidf_(float x) {
    return 1.0f / (1.0f + __expf(-x));
}
__device__ __forceinline__ float tanhf_(float x) {
    float e = __expf(2.0f * x);
    return 1.0f - 2.0f / (e + 1.0f);   // exact at +-inf, ~ulp-level error elsewhere
}
// lgkmcnt(0)-only barrier: LDS writes visible, but vmem loads STAY IN FLIGHT
// (__syncthreads would drain vmcnt(0) and kill the depth-2 prefetch)
__device__ __forceinline__ void lds_barrier() {
    asm volatile("s_waitcnt lgkmcnt(0)" ::: "memory");
    __builtin_amdgcn_s_barrier();
}

// ============================================================================
// xi GEMM: xi[tok][g] = sum_k hin[tok][k] * Wih[g][k]   (tok = b*TT + t)
// block = 512 thr: g = tid&127, tq = tid>>7 -> 8 tokens each; tile 32 tokens.
// Weight rows are L1-resident (24 KB of 64B lines reused across k-chunks).
__global__ __launch_bounds__(512, 4) void xi_gemm(
    const float* __restrict__ hin, const float* __restrict__ Wih,
    float* __restrict__ xi) {
    const int tid = threadIdx.x;
    const int g   = tid & 127;
    const int tq  = tid >> 7;
    const size_t tok0 = (size_t)blockIdx.x * 32;
    __shared__ __align__(16) float s_in[32][HH];
#pragma unroll
    for (int r = 0; r < 2; ++r) {
        int f4 = tid * 2 + r;
        int tk = f4 >> 5, k4 = (f4 & 31) << 2;
        *(float4*)&s_in[tk][k4] = *(const float4*)&hin[(tok0 + tk) * HH + k4];
    }
    __syncthreads();
    float acc[3][8];
#pragma unroll
    for (int i = 0; i < 3; ++i)
#pragma unroll
        for (int t = 0; t < 8; ++t) acc[i][t] = 0.0f;
    const float* w0 = Wih + (size_t)g * HH;
    const float* w1 = Wih + (size_t)(HH + g) * HH;
    const float* w2 = Wih + (size_t)(2 * HH + g) * HH;
#pragma unroll 2
    for (int kc = 0; kc < 32; ++kc) {
        float4 wa = *(const float4*)(w0 + kc * 4);
        float4 wb = *(const float4*)(w1 + kc * 4);
        float4 wc = *(const float4*)(w2 + kc * 4);
#pragma unroll
        for (int t = 0; t < 8; ++t) {
            float4 sv = *(const float4*)&s_in[tq * 8 + t][kc * 4];
            acc[0][t] = fmaf(wa.x, sv.x, acc[0][t]); acc[0][t] = fmaf(wa.y, sv.y, acc[0][t]);
            acc[0][t] = fmaf(wa.z, sv.z, acc[0][t]); acc[0][t] = fmaf(wa.w, sv.w, acc[0][t]);
            acc[1][t] = fmaf(wb.x, sv.x, acc[1][t]); acc[1][t] = fmaf(wb.y, sv.y, acc[1][t]);
            acc[1][t] = fmaf(wb.z, sv.z, acc[1][t]); acc[1][t] = fmaf(wb.w, sv.w, acc[1][t]);
            acc[2][t] = fmaf(wc.x, sv.x, acc[2][t]); acc[2][t] = fmaf(wc.y, sv.y, acc[2][t]);
            acc[2][t] = fmaf(wc.z, sv.z, acc[2][t]); acc[2][t] = fmaf(wc.w, sv.w, acc[2][t]);
        }
    }
#pragma unroll
    for (int i = 0; i < 3; ++i)
#pragma unroll
        for (int t = 0; t < 8; ++t)
            xi[(tok0 + tq * 8 + t) * G3 + i * HH + g] = acc[i][t];
}

// ============================================================================
// Recurrent kernel: h-matvec only (x-part precomputed as xi, except layer 1's
// tiny K=5 dot which stays fused). kt=tid&3 owns a 32-k slice, gt=tid>>2 owns
// hidden unit j (Whh rows {j,128+j,256+j} pinned in VGPRs: 96 floats).
// xi prefetched depth-2 in regs; loads cross lds_barrier() in flight.
template <bool FIRST, bool LAST>
__global__ __launch_bounds__(NTHR, 2) void gru_rec(
    const float* __restrict__ xin,   // FIRST: x (B,T,5); else xi (B,T,384)
    float* __restrict__ hout,        // !LAST: h sequence (B,T,128)
    const float* __restrict__ Wih5, const float* __restrict__ Whh,
    const float* __restrict__ bih, const float* __restrict__ bhh,
    const float* __restrict__ fcw, const float* __restrict__ fcb,
    float* __restrict__ fcout) {
    const int tid = threadIdx.x;
    const int kt  = tid & 3;
    const int gt  = tid >> 2;
    const int b0  = blockIdx.x * BB;

    __shared__ __align__(16) float s_h[2][BB][4][36];   // padded: slice kt -> banks 4kt..4kt+3
    __shared__ __align__(16) float s_xi[2][BB][G3];
    __shared__ float s_x5[2][BB][8];

    float wh[3][32];
#pragma unroll
    for (int i = 0; i < 3; ++i) {
        const float* wr = Whh + (size_t)(i * HH + gt) * HH + kt * 32;
#pragma unroll
        for (int j = 0; j < 32; j += 4) {
            float4 v = *(const float4*)(wr + j);
            wh[i][j] = v.x; wh[i][j + 1] = v.y; wh[i][j + 2] = v.z; wh[i][j + 3] = v.w;
        }
    }
#pragma unroll
    for (int i = 0; i < 3; ++i)
#pragma unroll
        for (int j = 0; j < 32; ++j) asm volatile("" : "+v"(wh[i][j]));

    float wx5[3][5];
    if constexpr (FIRST) {
#pragma unroll
        for (int i = 0; i < 3; ++i)
#pragma unroll
            for (int j = 0; j < 5; ++j) wx5[i][j] = Wih5[(i * HH + gt) * 5 + j];
    }

    const float br  = bih[gt] + bhh[gt];
    const float bz  = bih[HH + gt] + bhh[HH + gt];
    const float bxn = bih[2 * HH + gt];
    const float bhn = bhh[2 * HH + gt];

    if (tid < BB * HH) {
        int bb = tid >> 7, j = tid & (HH - 1);
        s_h[0][bb][j >> 5][j & 31] = 0.0f;
    }

    // ---- prologue: s_xi[0] <- xi(0); P0 <- xi(1); P1 <- xi(2) ----
    float4 P0 = make_float4(0.f, 0.f, 0.f, 0.f), P1 = P0;
    float  q0 = 0.f, q1 = 0.f;
    if constexpr (!FIRST) {
        if (tid < 192) {
            int bb = tid / 96, e = tid % 96;
            const float* base = xin + ((size_t)(b0 + bb) * TT) * G3 + e * 4;
            float4 v = *(const float4*)(base);
            P0 = *(const float4*)(base + (size_t)G3);
            P1 = *(const float4*)(base + (size_t)2 * G3);
            *(float4*)&s_xi[0][bb][e * 4] = v;
        }
    } else {
        if (tid < 16) {
            int bb = tid >> 3, k = tid & 7;
            if (k < 5) {
                const float* base = xin + ((size_t)(b0 + bb) * TT) * 5 + k;
                float v = base[0];
                q0 = base[5];
                q1 = base[10];
                s_x5[0][bb][k] = v;
            }
        }
    }
    __syncthreads();   // one-time full drain is fine here

#define REC_STEP(CUR, T, PV, QV)                                                   \
    {                                                                              \
        /* stage xi(T+1) -> s_xi[CUR^1]; issue load of xi(T+3) into PV */          \
        if constexpr (!FIRST) {                                                    \
            if (tid < 192) {                                                       \
                int bb = tid / 96, e = tid % 96;                                   \
                *(float4*)&s_xi[CUR ^ 1][bb][e * 4] = PV;                          \
                int tl = (T) + 3 < TT ? (T) + 3 : TT - 1;                          \
                PV = *(const float4*)(xin + ((size_t)(b0 + bb) * TT + tl) * G3 + e * 4); \
            }                                                                      \
        } else {                                                                   \
            if (tid < 16) {                                                        \
                int bb = tid >> 3, k = tid & 7;                                    \
                if (k < 5) {                                                       \
                    s_x5[CUR ^ 1][bb][k] = QV;                                     \
                    int tl = (T) + 3 < TT ? (T) + 3 : TT - 1;                      \
                    QV = xin[((size_t)(b0 + bb) * TT + tl) * 5 + k];               \
                }                                                                  \
            }                                                                      \
        }                                                                          \
        float a00 = 0.f, a01 = 0.f, a02 = 0.f, a10 = 0.f, a11 = 0.f, a12 = 0.f;    \
        const float* hp0 = &s_h[CUR][0][kt][0];                                    \
        const float* hp1 = &s_h[CUR][1][kt][0];                                    \
        _Pragma("unroll")                                                          \
        for (int jj = 0; jj < 32; jj += 4) {                                       \
            float4 u = *(const float4*)(hp0 + jj);                                 \
            float4 v = *(const float4*)(hp1 + jj);                                 \
            a00 = fmaf(wh[0][jj], u.x, a00); a00 = fmaf(wh[0][jj+1], u.y, a00);    \
            a00 = fmaf(wh[0][jj+2], u.z, a00); a00 = fmaf(wh[0][jj+3], u.w, a00);  \
            a01 = fmaf(wh[1][jj], u.x, a01); a01 = fmaf(wh[1][jj+1], u.y, a01);    \
            a01 = fmaf(wh[1][jj+2], u.z, a01); a01 = fmaf(wh[1][jj+3], u.w, a01);  \
            a02 = fmaf(wh[2][jj], u.x, a02); a02 = fmaf(wh[2][jj+1], u.y, a02);    \
            a02 = fmaf(wh[2][jj+2], u.z, a02); a02 = fmaf(wh[2][jj+3], u.w, a02);  \
            a10 = fmaf(wh[0][jj], v.x, a10); a10 = fmaf(wh[0][jj+1], v.y, a10);    \
            a10 = fmaf(wh[0][jj+2], v.z, a10); a10 = fmaf(wh[0][jj+3], v.w, a10);  \
            a11 = fmaf(wh[1][jj], v.x, a11); a11 = fmaf(wh[1][jj+1], v.y, a11);    \
            a11 = fmaf(wh[1][jj+2], v.z, a11); a11 = fmaf(wh[1][jj+3], v.w, a11);  \
            a12 = fmaf(wh[2][jj], v.x, a12); a12 = fmaf(wh[2][jj+1], v.y, a12);    \
            a12 = fmaf(wh[2][jj+2], v.z, a12); a12 = fmaf(wh[2][jj+3], v.w, a12);  \
        }                                                                          \
        a00 += __shfl_xor(a00, 1, 64); a00 += __shfl_xor(a00, 2, 64);              \
        a01 += __shfl_xor(a01, 1, 64); a01 += __shfl_xor(a01, 2, 64);              \
        a02 += __shfl_xor(a02, 1, 64); a02 += __shfl_xor(a02, 2, 64);              \
        a10 += __shfl_xor(a10, 1, 64); a10 += __shfl_xor(a10, 2, 64);              \
        a11 += __shfl_xor(a11, 1, 64); a11 += __shfl_xor(a11, 2, 64);              \
        a12 += __shfl_xor(a12, 1, 64); a12 += __shfl_xor(a12, 2, 64);              \
        if (kt < 2) {                                                              \
            const int bb = kt;                                                     \
            float cr  = (kt == 0) ? a00 : a10;                                     \
            float cz  = (kt == 0) ? a01 : a11;                                     \
            float cnh = (kt == 0) ? a02 : a12;                                     \
            float xr, xz, xn;                                                      \
            if constexpr (!FIRST) {                                                \
                xr = s_xi[CUR][bb][gt];                                            \
                xz = s_xi[CUR][bb][HH + gt];                                       \
                xn = s_xi[CUR][bb][2 * HH + gt];                                   \
            } else {                                                               \
                float x0 = s_x5[CUR][bb][0], x1 = s_x5[CUR][bb][1];                \
                float x2 = s_x5[CUR][bb][2], x3 = s_x5[CUR][bb][3];                \
                float x4 = s_x5[CUR][bb][4];                                       \
                xr = wx5[0][0]*x0 + wx5[0][1]*x1 + wx5[0][2]*x2 + wx5[0][3]*x3 + wx5[0][4]*x4; \
                xz = wx5[1][0]*x0 + wx5[1][1]*x1 + wx5[1][2]*x2 + wx5[1][3]*x3 + wx5[1][4]*x4; \
                xn = wx5[2][0]*x0 + wx5[2][1]*x1 + wx5[2][2]*x2 + wx5[2][3]*x3 + wx5[2][4]*x4; \
            }                                                                      \
            float r = sigmoidf_(xr + cr + br);                                     \
            float z = sigmoidf_(xz + cz + bz);                                     \
            float n = tanhf_(xn + bxn + r * (cnh + bhn));                          \
            float hp = s_h[CUR][bb][gt >> 5][gt & 31];                             \
            float hv = (1.0f - z) * n + z * hp;                                    \
            s_h[CUR ^ 1][bb][gt >> 5][gt & 31] = hv;                               \
            if constexpr (!LAST)                                                   \
                hout[((size_t)(b0 + bb) * TT + (T)) * HH + gt] = hv;               \
        }                                                                          \
        lds_barrier();                                                             \
    }

#pragma unroll 1
    for (int t = 0; t < TT; t += 2) {
        REC_STEP(0, t, P0, q0)
        REC_STEP(1, t + 1, P1, q1)
    }
#undef REC_STEP

    if constexpr (LAST) {
        if (tid < 128) {
            int bb = tid >> 6, l = tid & 63;
            float h0 = s_h[0][bb][l >> 5][l & 31];
            float h1 = s_h[0][bb][(l >> 5) + 2][l & 31];
            float s = h0 * fcw[l] + h1 * fcw[l + 64];
#pragma unroll
            for (int m = 32; m >= 1; m >>= 1) s += __shfl_xor(s, m, 64);
            if (l == 0) fcout[b0 + bb] = s + fcb[0];
        }
    }
}

// ============================================================================
// FALLBACK (ws too small for xi): round-4 fused kernel, proven correct.
template <int INK, bool LAST>
__global__ __launch_bounds__(NTHR, 2) void gru_fused(
    const float* in, float* out,
    const float* __restrict__ Wih, const float* __restrict__ Whh,
    const float* __restrict__ bih, const float* __restrict__ bhh,
    const float* __restrict__ fcw, const float* __restrict__ fcb,
    float* __restrict__ fcout) {
    const int tid = threadIdx.x;
    const int kt  = tid & 3;
    const int gt  = tid >> 2;
    const int b0  = blockIdx.x * BB;
    __shared__ __align__(16) float s_h[2][BB][4][36];
    __shared__ __align__(16) float s_x[2][BB][(INK == 5) ? 8 : 144];
    float wh[3][32];
#pragma unroll
    for (int i = 0; i < 3; ++i) {
        const float* wr = Whh + (size_t)(i * HH + gt) * HH + kt * 32;
#pragma unroll
        for (int j = 0; j < 32; j += 4) {
            float4 v = *(const float4*)(wr + j);
            wh[i][j] = v.x; wh[i][j + 1] = v.y; wh[i][j + 2] = v.z; wh[i][j + 3] = v.w;
        }
    }
#pragma unroll
    for (int i = 0; i < 3; ++i)
#pragma unroll
        for (int j = 0; j < 32; ++j) asm volatile("" : "+v"(wh[i][j]));
    float wx[3][32]; float wx5[3][5];
    if constexpr (INK == 128) {
#pragma unroll
        for (int i = 0; i < 3; ++i) {
            const float* wr = Wih + (size_t)(i * HH + gt) * HH + kt * 32;
#pragma unroll
            for (int j = 0; j < 32; j += 4) {
                float4 v = *(const float4*)(wr + j);
                wx[i][j] = v.x; wx[i][j + 1] = v.y; wx[i][j + 2] = v.z; wx[i][j + 3] = v.w;
            }
        }
#pragma unroll
        for (int i = 0; i < 3; ++i)
#pragma unroll
            for (int j = 0; j < 32; ++j) asm volatile("" : "+v"(wx[i][j]));
    } else {
#pragma unroll
        for (int i = 0; i < 3; ++i)
#pragma unroll
            for (int j = 0; j < 5; ++j) wx5[i][j] = Wih[(i * HH + gt) * 5 + j];
    }
    const float br  = bih[gt] + bhh[gt];
    const float bz  = bih[HH + gt] + bhh[HH + gt];
    const float bxn = bih[2 * HH + gt];
    const float bhn = bhh[2 * HH + gt];
    if (tid < BB * HH) {
        int bb = tid >> 7, j = tid & (HH - 1);
        s_h[0][bb][j >> 5][j & 31] = 0.0f;
    }
    if constexpr (INK == 5) {
        if (tid < BB * 5) {
            int bb = tid / 5, k = tid % 5;
            s_x[0][bb][k] = in[((size_t)(b0 + bb) * TT) * 5 + k];
        }
    } else {
        if (tid < 64) {
            int row = tid >> 5, f = (tid & 31) * 4;
            float4 v = *(const float4*)&in[((size_t)(b0 + row) * TT) * HH + f];
            *(float4*)&s_x[0][row][(f >> 5) * 36 + (f & 31)] = v;
        }
    }
    __syncthreads();
    for (int t = 0; t < TT; ++t) {
        const int cur = t & 1, nxt = cur ^ 1;
        float4 xs4 = make_float4(0.f, 0.f, 0.f, 0.f);
        float  xs1 = 0.f;
        if constexpr (INK == 5) {
            if (tid < BB * 5 && t + 1 < TT) {
                int bb = tid / 5, k = tid % 5;
                xs1 = in[((size_t)(b0 + bb) * TT + (t + 1)) * 5 + k];
            }
        } else {
            if (tid < 64 && t + 1 < TT) {
                int row = tid >> 5, f = (tid & 31) * 4;
                xs4 = *(const float4*)&in[((size_t)(b0 + row) * TT + (t + 1)) * HH + f];
            }
        }
        float acc[BB][4];
#pragma unroll
        for (int bb = 0; bb < BB; ++bb) {
            acc[bb][0] = 0.f; acc[bb][1] = 0.f; acc[bb][2] = 0.f; acc[bb][3] = 0.f;
        }
#pragma unroll
        for (int bb = 0; bb < BB; ++bb) {
            const float* hp = &s_h[cur][bb][kt][0];
            const float* xp = &s_x[cur][bb][(INK == 5) ? 0 : kt * 36];
#pragma unroll
            for (int jj = 0; jj < 32; jj += 4) {
                float4 hu = *(const float4*)(hp + jj);
                acc[bb][0] = fmaf(wh[0][jj], hu.x, acc[bb][0]);
                acc[bb][0] = fmaf(wh[0][jj+1], hu.y, acc[bb][0]);
                acc[bb][0] = fmaf(wh[0][jj+2], hu.z, acc[bb][0]);
                acc[bb][0] = fmaf(wh[0][jj+3], hu.w, acc[bb][0]);
                acc[bb][1] = fmaf(wh[1][jj], hu.x, acc[bb][1]);
                acc[bb][1] = fmaf(wh[1][jj+1], hu.y, acc[bb][1]);
                acc[bb][1] = fmaf(wh[1][jj+2], hu.z, acc[bb][1]);
                acc[bb][1] = fmaf(wh[1][jj+3], hu.w, acc[bb][1]);
                acc[bb][3] = fmaf(wh[2][jj], hu.x, acc[bb][3]);
                acc[bb][3] = fmaf(wh[2][jj+1], hu.y, acc[bb][3]);
                acc[bb][3] = fmaf(wh[2][jj+2], hu.z, acc[bb][3]);
                acc[bb][3] = fmaf(wh[2][jj+3], hu.w, acc[bb][3]);
                if constexpr (INK == 128) {
                    float4 xu = *(const float4*)(xp + jj);
                    acc[bb][0] = fmaf(wx[0][jj], xu.x, acc[bb][0]);
                    acc[bb][0] = fmaf(wx[0][jj+1], xu.y, acc[bb][0]);
                    acc[bb][0] = fmaf(wx[0][jj+2], xu.z, acc[bb][0]);
                    acc[bb][0] = fmaf(wx[0][jj+3], xu.w, acc[bb][0]);
                    acc[bb][1] = fmaf(wx[1][jj], xu.x, acc[bb][1]);
                    acc[bb][1] = fmaf(wx[1][jj+1], xu.y, acc[bb][1]);
                    acc[bb][1] = fmaf(wx[1][jj+2], xu.z, acc[bb][1]);
                    acc[bb][1] = fmaf(wx[1][jj+3], xu.w, acc[bb][1]);
                    acc[bb][2] = fmaf(wx[2][jj], xu.x, acc[bb][2]);
                    acc[bb][2] = fmaf(wx[2][jj+1], xu.y, acc[bb][2]);
                    acc[bb][2] = fmaf(wx[2][jj+2], xu.z, acc[bb][2]);
                    acc[bb][2] = fmaf(wx[2][jj+3], xu.w, acc[bb][2]);
                }
            }
        }
#pragma unroll
        for (int bb = 0; bb < BB; ++bb)
#pragma unroll
            for (int g = 0; g < 4; ++g) {
                if (INK == 5 && g == 2) continue;
                acc[bb][g] += __shfl_xor(acc[bb][g], 1, 64);
                acc[bb][g] += __shfl_xor(acc[bb][g], 2, 64);
            }
        if (kt < 2) {
            const int bb = kt;
            float cr  = (kt == 0) ? acc[0][0] : acc[1][0];
            float cz  = (kt == 0) ? acc[0][1] : acc[1][1];
            float cnx = (kt == 0) ? acc[0][2] : acc[1][2];
            float cnh = (kt == 0) ? acc[0][3] : acc[1][3];
            if constexpr (INK == 5) {
                float x0 = s_x[cur][bb][0], x1 = s_x[cur][bb][1], x2 = s_x[cur][bb][2];
                float x3 = s_x[cur][bb][3], x4 = s_x[cur][bb][4];
                cr += wx5[0][0]*x0 + wx5[0][1]*x1 + wx5[0][2]*x2 + wx5[0][3]*x3 + wx5[0][4]*x4;
                cz += wx5[1][0]*x0 + wx5[1][1]*x1 + wx5[1][2]*x2 + wx5[1][3]*x3 + wx5[1][4]*x4;
                cnx = wx5[2][0]*x0 + wx5[2][1]*x1 + wx5[2][2]*x2 + wx5[2][3]*x3 + wx5[2][4]*x4;
            }
            float r = sigmoidf_(cr + br);
            float z = sigmoidf_(cz + bz);
            float n = tanhf_(cnx + bxn + r * (cnh + bhn));
            float hp = s_h[cur][bb][gt >> 5][gt & 31];
            float hv = (1.0f - z) * n + z * hp;
            s_h[nxt][bb][gt >> 5][gt & 31] = hv;
            if (!LAST) out[((size_t)(b0 + bb) * TT + t) * HH + gt] = hv;
        }
        if constexpr (INK == 5) {
            if (tid < BB * 5 && t + 1 < TT) {
                int bb = tid / 5, k = tid % 5;
                s_x[nxt][bb][k] = xs1;
            }
        } else {
            if (tid < 64 && t + 1 < TT) {
                int row = tid >> 5, f = (tid & 31) * 4;
                *(float4*)&s_x[nxt][row][(f >> 5) * 36 + (f & 31)] = xs4;
            }
        }
        __syncthreads();
    }
    if (LAST) {
        if (tid < 128) {
            int bb = tid >> 6, l = tid & 63;
            float h0 = s_h[0][bb][l >> 5][l & 31];
            float h1 = s_h[0][bb][(l >> 5) + 2][l & 31];
            float s = h0 * fcw[l] + h1 * fcw[l + 64];
#pragma unroll
            for (int m = 32; m >= 1; m >>= 1) s += __shfl_xor(s, m, 64);
            if (l == 0) fcout[b0 + bb] = s + fcb[0];
        }
    }
}

extern "C" void kernel_launch(void* const* d_in, const int* in_sizes, int n_in,
                              void* d_out, int out_size, void* d_ws, size_t ws_size,
                              hipStream_t stream) {
    const float* x    = (const float*)d_in[0];
    const float* Wih0 = (const float*)d_in[1];
    const float* Whh0 = (const float*)d_in[2];
    const float* bih0 = (const float*)d_in[3];
    const float* bhh0 = (const float*)d_in[4];
    const float* WihR = (const float*)d_in[5];
    const float* WhhR = (const float*)d_in[6];
    const float* bihR = (const float*)d_in[7];
    const float* bhhR = (const float*)d_in[8];
    const float* fcw  = (const float*)d_in[9];
    const float* fcb  = (const float*)d_in[10];

    const size_t BUF_B = (size_t)BTOT * TT * HH * 4;   // 134,217,728
    const size_t XI_B  = (size_t)BTOT * TT * G3 * 4;   // 402,653,184
    float* buf = (float*)d_ws;

    if (ws_size >= BUF_B + XI_B) {
        float* xi = (float*)((char*)d_ws + BUF_B);
        const int GB = (BTOT * TT) / 32;   // 8192 GEMM blocks
        gru_rec<true, false><<<NBLK, NTHR, 0, stream>>>(x, buf, Wih0, Whh0, bih0, bhh0,
                                                        nullptr, nullptr, nullptr);
        for (int l = 0; l < 3; ++l) {
            xi_gemm<<<GB, 512, 0, stream>>>(buf, WihR + (size_t)l * G3 * HH, xi);
            if (l < 2)
                gru_rec<false, false><<<NBLK, NTHR, 0, stream>>>(
                    xi, buf, nullptr, WhhR + (size_t)l * G3 * HH, bihR + l * G3,
                    bhhR + l * G3, nullptr, nullptr, nullptr);
            else
                gru_rec<false, true><<<NBLK, NTHR, 0, stream>>>(
                    xi, buf, nullptr, WhhR + (size_t)l * G3 * HH, bihR + l * G3,
                    bhhR + l * G3, fcw, fcb, (float*)d_out);
        }
    } else {
        gru_fused<5, false><<<NBLK, NTHR, 0, stream>>>(x, buf, Wih0, Whh0, bih0, bhh0,
                                                       nullptr, nullptr, nullptr);
        gru_fused<128, false><<<NBLK, NTHR, 0, stream>>>(buf, buf, WihR, WhhR, bihR, bhhR,
                                                         nullptr, nullptr, nullptr);
        gru_fused<128, false><<<NBLK, NTHR, 0, stream>>>(buf, buf, WihR + G3 * HH,
                                                         WhhR + G3 * HH, bihR + G3,
                                                         bhhR + G3, nullptr, nullptr, nullptr);
        gru_fused<128, true><<<NBLK, NTHR, 0, stream>>>(buf, buf, WihR + 2 * G3 * HH,
                                                        WhhR + 2 * G3 * HH, bihR + 2 * G3,
                                                        bhhR + 2 * G3, fcw, fcb, (float*)d_out);
    }
}

// Round 7
// 3303.460 us; speedup vs baseline: 5.5812x; 1.0027x over previous
//
#include <hip/hip_runtime.h>
#include <cmath>

#define HH   128
#define G3   384
#define TT   512
#define BTOT 512
#define BB   2
#define NBLK (BTOT / BB)   // 256 blocks = 1 per CU
#define NTHR 512           // 8 waves, 2/SIMD

__device__ __forceinline__ float sigmoidf_(float x) {
    return 1.0f / (1.0f + __expf(-x));
}
__device__ __forceinline__ float tanhf_(float x) {
    float e = __expf(2.0f * x);
    return 1.0f - 2.0f / (e + 1.0f);   // exact at +-inf, ~ulp-level error elsewhere
}
// lgkmcnt(0)-only barrier: LDS writes visible, but vmem loads STAY IN FLIGHT
// (__syncthreads would drain vmcnt(0) and kill the depth-2 prefetch)
__device__ __forceinline__ void lds_barrier() {
    asm volatile("s_waitcnt lgkmcnt(0)" ::: "memory");
    __builtin_amdgcn_s_barrier();
}

// ============================================================================
// xi GEMM: xi[tok][g] = sum_k hin[tok][k] * Wih[g][k]   (tok = b*TT + t)
// block = 512 thr: g = tid&127, tq = tid>>7 -> 8 tokens each; tile 32 tokens.
// Weight rows are L1-resident (24 KB of 64B lines reused across k-chunks).
__global__ __launch_bounds__(512, 4) void xi_gemm(
    const float* __restrict__ hin, const float* __restrict__ Wih,
    float* __restrict__ xi) {
    const int tid = threadIdx.x;
    const int g   = tid & 127;
    const int tq  = tid >> 7;
    const size_t tok0 = (size_t)blockIdx.x * 32;
    __shared__ __align__(16) float s_in[32][HH];
#pragma unroll
    for (int r = 0; r < 2; ++r) {
        int f4 = tid * 2 + r;
        int tk = f4 >> 5, k4 = (f4 & 31) << 2;
        *(float4*)&s_in[tk][k4] = *(const float4*)&hin[(tok0 + tk) * HH + k4];
    }
    __syncthreads();
    float acc[3][8];
#pragma unroll
    for (int i = 0; i < 3; ++i)
#pragma unroll
        for (int t = 0; t < 8; ++t) acc[i][t] = 0.0f;
    const float* w0 = Wih + (size_t)g * HH;
    const float* w1 = Wih + (size_t)(HH + g) * HH;
    const float* w2 = Wih + (size_t)(2 * HH + g) * HH;
#pragma unroll 2
    for (int kc = 0; kc < 32; ++kc) {
        float4 wa = *(const float4*)(w0 + kc * 4);
        float4 wb = *(const float4*)(w1 + kc * 4);
        float4 wc = *(const float4*)(w2 + kc * 4);
#pragma unroll
        for (int t = 0; t < 8; ++t) {
            float4 sv = *(const float4*)&s_in[tq * 8 + t][kc * 4];
            acc[0][t] = fmaf(wa.x, sv.x, acc[0][t]); acc[0][t] = fmaf(wa.y, sv.y, acc[0][t]);
            acc[0][t] = fmaf(wa.z, sv.z, acc[0][t]); acc[0][t] = fmaf(wa.w, sv.w, acc[0][t]);
            acc[1][t] = fmaf(wb.x, sv.x, acc[1][t]); acc[1][t] = fmaf(wb.y, sv.y, acc[1][t]);
            acc[1][t] = fmaf(wb.z, sv.z, acc[1][t]); acc[1][t] = fmaf(wb.w, sv.w, acc[1][t]);
            acc[2][t] = fmaf(wc.x, sv.x, acc[2][t]); acc[2][t] = fmaf(wc.y, sv.y, acc[2][t]);
            acc[2][t] = fmaf(wc.z, sv.z, acc[2][t]); acc[2][t] = fmaf(wc.w, sv.w, acc[2][t]);
        }
    }
#pragma unroll
    for (int i = 0; i < 3; ++i)
#pragma unroll
        for (int t = 0; t < 8; ++t)
            xi[(tok0 + tq * 8 + t) * G3 + i * HH + g] = acc[i][t];
}

// ============================================================================
// Recurrent kernel: h-matvec only (x-part precomputed as xi, except layer 1's
// tiny K=5 dot which stays fused). kt=tid&3 owns a 32-k slice, gt=tid>>2 owns
// hidden unit j (Whh rows {j,128+j,256+j} pinned in VGPRs: 96 floats).
// xi prefetched depth-2 in regs; loads cross lds_barrier() in flight.
template <bool FIRST, bool LAST>
__global__ __launch_bounds__(NTHR, 2) void gru_rec(
    const float* __restrict__ xin,   // FIRST: x (B,T,5); else xi (B,T,384)
    float* __restrict__ hout,        // !LAST: h sequence (B,T,128)
    const float* __restrict__ Wih5, const float* __restrict__ Whh,
    const float* __restrict__ bih, const float* __restrict__ bhh,
    const float* __restrict__ fcw, const float* __restrict__ fcb,
    float* __restrict__ fcout) {
    const int tid = threadIdx.x;
    const int kt  = tid & 3;
    const int gt  = tid >> 2;
    const int b0  = blockIdx.x * BB;

    __shared__ __align__(16) float s_h[2][BB][4][36];   // padded: slice kt -> banks 4kt..4kt+3
    __shared__ __align__(16) float s_xi[2][BB][G3];
    __shared__ float s_x5[2][BB][8];

    float wh[3][32];
#pragma unroll
    for (int i = 0; i < 3; ++i) {
        const float* wr = Whh + (size_t)(i * HH + gt) * HH + kt * 32;
#pragma unroll
        for (int j = 0; j < 32; j += 4) {
            float4 v = *(const float4*)(wr + j);
            wh[i][j] = v.x; wh[i][j + 1] = v.y; wh[i][j + 2] = v.z; wh[i][j + 3] = v.w;
        }
    }
#pragma unroll
    for (int i = 0; i < 3; ++i)
#pragma unroll
        for (int j = 0; j < 32; ++j) asm volatile("" : "+v"(wh[i][j]));

    float wx5[3][5];
    if constexpr (FIRST) {
#pragma unroll
        for (int i = 0; i < 3; ++i)
#pragma unroll
            for (int j = 0; j < 5; ++j) wx5[i][j] = Wih5[(i * HH + gt) * 5 + j];
    }

    const float br  = bih[gt] + bhh[gt];
    const float bz  = bih[HH + gt] + bhh[HH + gt];
    const float bxn = bih[2 * HH + gt];
    const float bhn = bhh[2 * HH + gt];

    if (tid < BB * HH) {
        int bb = tid >> 7, j = tid & (HH - 1);
        s_h[0][bb][j >> 5][j & 31] = 0.0f;
    }

    // ---- prologue: s_xi[0] <- xi(0); P0 <- xi(1); P1 <- xi(2) ----
    float4 P0 = make_float4(0.f, 0.f, 0.f, 0.f), P1 = P0;
    float  q0 = 0.f, q1 = 0.f;
    if constexpr (!FIRST) {
        if (tid < 192) {
            int bb = tid / 96, e = tid % 96;
            const float* base = xin + ((size_t)(b0 + bb) * TT) * G3 + e * 4;
            float4 v = *(const float4*)(base);
            P0 = *(const float4*)(base + (size_t)G3);
            P1 = *(const float4*)(base + (size_t)2 * G3);
            *(float4*)&s_xi[0][bb][e * 4] = v;
        }
    } else {
        if (tid < 16) {
            int bb = tid >> 3, k = tid & 7;
            if (k < 5) {
                const float* base = xin + ((size_t)(b0 + bb) * TT) * 5 + k;
                float v = base[0];
                q0 = base[5];
                q1 = base[10];
                s_x5[0][bb][k] = v;
            }
        }
    }
    __syncthreads();   // one-time full drain is fine here

#define REC_STEP(CUR, T, PV, QV)                                                   \
    {                                                                              \
        /* stage xi(T+1) -> s_xi[CUR^1]; issue load of xi(T+3) into PV */          \
        if constexpr (!FIRST) {                                                    \
            if (tid < 192) {                                                       \
                int bb = tid / 96, e = tid % 96;                                   \
                *(float4*)&s_xi[CUR ^ 1][bb][e * 4] = PV;                          \
                int tl = (T) + 3 < TT ? (T) + 3 : TT - 1;                          \
                PV = *(const float4*)(xin + ((size_t)(b0 + bb) * TT + tl) * G3 + e * 4); \
            }                                                                      \
        } else {                                                                   \
            if (tid < 16) {                                                        \
                int bb = tid >> 3, k = tid & 7;                                    \
                if (k < 5) {                                                       \
                    s_x5[CUR ^ 1][bb][k] = QV;                                     \
                    int tl = (T) + 3 < TT ? (T) + 3 : TT - 1;                      \
                    QV = xin[((size_t)(b0 + bb) * TT + tl) * 5 + k];               \
                }                                                                  \
            }                                                                      \
        }                                                                          \
        float a00 = 0.f, a01 = 0.f, a02 = 0.f, a10 = 0.f, a11 = 0.f, a12 = 0.f;    \
        const float* hp0 = &s_h[CUR][0][kt][0];                                    \
        const float* hp1 = &s_h[CUR][1][kt][0];                                    \
        _Pragma("unroll")                                                          \
        for (int jj = 0; jj < 32; jj += 4) {                                       \
            float4 u = *(const float4*)(hp0 + jj);                                 \
            float4 v = *(const float4*)(hp1 + jj);                                 \
            a00 = fmaf(wh[0][jj], u.x, a00); a00 = fmaf(wh[0][jj+1], u.y, a00);    \
            a00 = fmaf(wh[0][jj+2], u.z, a00); a00 = fmaf(wh[0][jj+3], u.w, a00);  \
            a01 = fmaf(wh[1][jj], u.x, a01); a01 = fmaf(wh[1][jj+1], u.y, a01);    \
            a01 = fmaf(wh[1][jj+2], u.z, a01); a01 = fmaf(wh[1][jj+3], u.w, a01);  \
            a02 = fmaf(wh[2][jj], u.x, a02); a02 = fmaf(wh[2][jj+1], u.y, a02);    \
            a02 = fmaf(wh[2][jj+2], u.z, a02); a02 = fmaf(wh[2][jj+3], u.w, a02);  \
            a10 = fmaf(wh[0][jj], v.x, a10); a10 = fmaf(wh[0][jj+1], v.y, a10);    \
            a10 = fmaf(wh[0][jj+2], v.z, a10); a10 = fmaf(wh[0][jj+3], v.w, a10);  \
            a11 = fmaf(wh[1][jj], v.x, a11); a11 = fmaf(wh[1][jj+1], v.y, a11);    \
            a11 = fmaf(wh[1][jj+2], v.z, a11); a11 = fmaf(wh[1][jj+3], v.w, a11);  \
            a12 = fmaf(wh[2][jj], v.x, a12); a12 = fmaf(wh[2][jj+1], v.y, a12);    \
            a12 = fmaf(wh[2][jj+2], v.z, a12); a12 = fmaf(wh[2][jj+3], v.w, a12);  \
        }                                                                          \
        a00 += __shfl_xor(a00, 1, 64); a00 += __shfl_xor(a00, 2, 64);              \
        a01 += __shfl_xor(a01, 1, 64); a01 += __shfl_xor(a01, 2, 64);              \
        a02 += __shfl_xor(a02, 1, 64); a02 += __shfl_xor(a02, 2, 64);              \
        a10 += __shfl_xor(a10, 1, 64); a10 += __shfl_xor(a10, 2, 64);              \
        a11 += __shfl_xor(a11, 1, 64); a11 += __shfl_xor(a11, 2, 64);              \
        a12 += __shfl_xor(a12, 1, 64); a12 += __shfl_xor(a12, 2, 64);              \
        if (kt < 2) {                                                              \
            const int bb = kt;                                                     \
            float cr  = (kt == 0) ? a00 : a10;                                     \
            float cz  = (kt == 0) ? a01 : a11;                                     \
            float cnh = (kt == 0) ? a02 : a12;                                     \
            float xr, xz, xn;                                                      \
            if constexpr (!FIRST) {                                                \
                xr = s_xi[CUR][bb][gt];                                            \
                xz = s_xi[CUR][bb][HH + gt];                                       \
                xn = s_xi[CUR][bb][2 * HH + gt];                                   \
            } else {                                                               \
                float x0 = s_x5[CUR][bb][0], x1 = s_x5[CUR][bb][1];                \
                float x2 = s_x5[CUR][bb][2], x3 = s_x5[CUR][bb][3];                \
                float x4 = s_x5[CUR][bb][4];                                       \
                xr = wx5[0][0]*x0 + wx5[0][1]*x1 + wx5[0][2]*x2 + wx5[0][3]*x3 + wx5[0][4]*x4; \
                xz = wx5[1][0]*x0 + wx5[1][1]*x1 + wx5[1][2]*x2 + wx5[1][3]*x3 + wx5[1][4]*x4; \
                xn = wx5[2][0]*x0 + wx5[2][1]*x1 + wx5[2][2]*x2 + wx5[2][3]*x3 + wx5[2][4]*x4; \
            }                                                                      \
            float r = sigmoidf_(xr + cr + br);                                     \
            float z = sigmoidf_(xz + cz + bz);                                     \
            float n = tanhf_(xn + bxn + r * (cnh + bhn));                          \
            float hp = s_h[CUR][bb][gt >> 5][gt & 31];                             \
            float hv = (1.0f - z) * n + z * hp;                                    \
            s_h[CUR ^ 1][bb][gt >> 5][gt & 31] = hv;                               \
            if constexpr (!LAST)                                                   \
                hout[((size_t)(b0 + bb) * TT + (T)) * HH + gt] = hv;               \
        }                                                                          \
        lds_barrier();                                                             \
    }

#pragma unroll 1
    for (int t = 0; t < TT; t += 2) {
        REC_STEP(0, t, P0, q0)
        REC_STEP(1, t + 1, P1, q1)
    }
#undef REC_STEP

    if constexpr (LAST) {
        if (tid < 128) {
            int bb = tid >> 6, l = tid & 63;
            float h0 = s_h[0][bb][l >> 5][l & 31];
            float h1 = s_h[0][bb][(l >> 5) + 2][l & 31];
            float s = h0 * fcw[l] + h1 * fcw[l + 64];
#pragma unroll
            for (int m = 32; m >= 1; m >>= 1) s += __shfl_xor(s, m, 64);
            if (l == 0) fcout[b0 + bb] = s + fcb[0];
        }
    }
}

// ============================================================================
// FALLBACK (ws too small for xi): round-4 fused kernel, proven correct.
template <int INK, bool LAST>
__global__ __launch_bounds__(NTHR, 2) void gru_fused(
    const float* in, float* out,
    const float* __restrict__ Wih, const float* __restrict__ Whh,
    const float* __restrict__ bih, const float* __restrict__ bhh,
    const float* __restrict__ fcw, const float* __restrict__ fcb,
    float* __restrict__ fcout) {
    const int tid = threadIdx.x;
    const int kt  = tid & 3;
    const int gt  = tid >> 2;
    const int b0  = blockIdx.x * BB;
    __shared__ __align__(16) float s_h[2][BB][4][36];
    __shared__ __align__(16) float s_x[2][BB][(INK == 5) ? 8 : 144];
    float wh[3][32];
#pragma unroll
    for (int i = 0; i < 3; ++i) {
        const float* wr = Whh + (size_t)(i * HH + gt) * HH + kt * 32;
#pragma unroll
        for (int j = 0; j < 32; j += 4) {
            float4 v = *(const float4*)(wr + j);
            wh[i][j] = v.x; wh[i][j + 1] = v.y; wh[i][j + 2] = v.z; wh[i][j + 3] = v.w;
        }
    }
#pragma unroll
    for (int i = 0; i < 3; ++i)
#pragma unroll
        for (int j = 0; j < 32; ++j) asm volatile("" : "+v"(wh[i][j]));
    float wx[3][32]; float wx5[3][5];
    if constexpr (INK == 128) {
#pragma unroll
        for (int i = 0; i < 3; ++i) {
            const float* wr = Wih + (size_t)(i * HH + gt) * HH + kt * 32;
#pragma unroll
            for (int j = 0; j < 32; j += 4) {
                float4 v = *(const float4*)(wr + j);
                wx[i][j] = v.x; wx[i][j + 1] = v.y; wx[i][j + 2] = v.z; wx[i][j + 3] = v.w;
            }
        }
#pragma unroll
        for (int i = 0; i < 3; ++i)
#pragma unroll
            for (int j = 0; j < 32; ++j) asm volatile("" : "+v"(wx[i][j]));
    } else {
#pragma unroll
        for (int i = 0; i < 3; ++i)
#pragma unroll
            for (int j = 0; j < 5; ++j) wx5[i][j] = Wih[(i * HH + gt) * 5 + j];
    }
    const float br  = bih[gt] + bhh[gt];
    const float bz  = bih[HH + gt] + bhh[HH + gt];
    const float bxn = bih[2 * HH + gt];
    const float bhn = bhh[2 * HH + gt];
    if (tid < BB * HH) {
        int bb = tid >> 7, j = tid & (HH - 1);
        s_h[0][bb][j >> 5][j & 31] = 0.0f;
    }
    if constexpr (INK == 5) {
        if (tid < BB * 5) {
            int bb = tid / 5, k = tid % 5;
            s_x[0][bb][k] = in[((size_t)(b0 + bb) * TT) * 5 + k];
        }
    } else {
        if (tid < 64) {
            int row = tid >> 5, f = (tid & 31) * 4;
            float4 v = *(const float4*)&in[((size_t)(b0 + row) * TT) * HH + f];
            *(float4*)&s_x[0][row][(f >> 5) * 36 + (f & 31)] = v;
        }
    }
    __syncthreads();
    for (int t = 0; t < TT; ++t) {
        const int cur = t & 1, nxt = cur ^ 1;
        float4 xs4 = make_float4(0.f, 0.f, 0.f, 0.f);
        float  xs1 = 0.f;
        if constexpr (INK == 5) {
            if (tid < BB * 5 && t + 1 < TT) {
                int bb = tid / 5, k = tid % 5;
                xs1 = in[((size_t)(b0 + bb) * TT + (t + 1)) * 5 + k];
            }
        } else {
            if (tid < 64 && t + 1 < TT) {
                int row = tid >> 5, f = (tid & 31) * 4;
                xs4 = *(const float4*)&in[((size_t)(b0 + row) * TT + (t + 1)) * HH + f];
            }
        }
        float acc[BB][4];
#pragma unroll
        for (int bb = 0; bb < BB; ++bb) {
            acc[bb][0] = 0.f; acc[bb][1] = 0.f; acc[bb][2] = 0.f; acc[bb][3] = 0.f;
        }
#pragma unroll
        for (int bb = 0; bb < BB; ++bb) {
            const float* hp = &s_h[cur][bb][kt][0];
            const float* xp = &s_x[cur][bb][(INK == 5) ? 0 : kt * 36];
#pragma unroll
            for (int jj = 0; jj < 32; jj += 4) {
                float4 hu = *(const float4*)(hp + jj);
                acc[bb][0] = fmaf(wh[0][jj], hu.x, acc[bb][0]);
                acc[bb][0] = fmaf(wh[0][jj+1], hu.y, acc[bb][0]);
                acc[bb][0] = fmaf(wh[0][jj+2], hu.z, acc[bb][0]);
                acc[bb][0] = fmaf(wh[0][jj+3], hu.w, acc[bb][0]);
                acc[bb][1] = fmaf(wh[1][jj], hu.x, acc[bb][1]);
                acc[bb][1] = fmaf(wh[1][jj+1], hu.y, acc[bb][1]);
                acc[bb][1] = fmaf(wh[1][jj+2], hu.z, acc[bb][1]);
                acc[bb][1] = fmaf(wh[1][jj+3], hu.w, acc[bb][1]);
                acc[bb][3] = fmaf(wh[2][jj], hu.x, acc[bb][3]);
                acc[bb][3] = fmaf(wh[2][jj+1], hu.y, acc[bb][3]);
                acc[bb][3] = fmaf(wh[2][jj+2], hu.z, acc[bb][3]);
                acc[bb][3] = fmaf(wh[2][jj+3], hu.w, acc[bb][3]);
                if constexpr (INK == 128) {
                    float4 xu = *(const float4*)(xp + jj);
                    acc[bb][0] = fmaf(wx[0][jj], xu.x, acc[bb][0]);
                    acc[bb][0] = fmaf(wx[0][jj+1], xu.y, acc[bb][0]);
                    acc[bb][0] = fmaf(wx[0][jj+2], xu.z, acc[bb][0]);
                    acc[bb][0] = fmaf(wx[0][jj+3], xu.w, acc[bb][0]);
                    acc[bb][1] = fmaf(wx[1][jj], xu.x, acc[bb][1]);
                    acc[bb][1] = fmaf(wx[1][jj+1], xu.y, acc[bb][1]);
                    acc[bb][1] = fmaf(wx[1][jj+2], xu.z, acc[bb][1]);
                    acc[bb][1] = fmaf(wx[1][jj+3], xu.w, acc[bb][1]);
                    acc[bb][2] = fmaf(wx[2][jj], xu.x, acc[bb][2]);
                    acc[bb][2] = fmaf(wx[2][jj+1], xu.y, acc[bb][2]);
                    acc[bb][2] = fmaf(wx[2][jj+2], xu.z, acc[bb][2]);
                    acc[bb][2] = fmaf(wx[2][jj+3], xu.w, acc[bb][2]);
                }
            }
        }
#pragma unroll
        for (int bb = 0; bb < BB; ++bb)
#pragma unroll
            for (int g = 0; g < 4; ++g) {
                if (INK == 5 && g == 2) continue;
                acc[bb][g] += __shfl_xor(acc[bb][g], 1, 64);
                acc[bb][g] += __shfl_xor(acc[bb][g], 2, 64);
            }
        if (kt < 2) {
            const int bb = kt;
            float cr  = (kt == 0) ? acc[0][0] : acc[1][0];
            float cz  = (kt == 0) ? acc[0][1] : acc[1][1];
            float cnx = (kt == 0) ? acc[0][2] : acc[1][2];
            float cnh = (kt == 0) ? acc[0][3] : acc[1][3];
            if constexpr (INK == 5) {
                float x0 = s_x[cur][bb][0], x1 = s_x[cur][bb][1], x2 = s_x[cur][bb][2];
                float x3 = s_x[cur][bb][3], x4 = s_x[cur][bb][4];
                cr += wx5[0][0]*x0 + wx5[0][1]*x1 + wx5[0][2]*x2 + wx5[0][3]*x3 + wx5[0][4]*x4;
                cz += wx5[1][0]*x0 + wx5[1][1]*x1 + wx5[1][2]*x2 + wx5[1][3]*x3 + wx5[1][4]*x4;
                cnx = wx5[2][0]*x0 + wx5[2][1]*x1 + wx5[2][2]*x2 + wx5[2][3]*x3 + wx5[2][4]*x4;
            }
            float r = sigmoidf_(cr + br);
            float z = sigmoidf_(cz + bz);
            float n = tanhf_(cnx + bxn + r * (cnh + bhn));
            float hp = s_h[cur][bb][gt >> 5][gt & 31];
            float hv = (1.0f - z) * n + z * hp;
            s_h[nxt][bb][gt >> 5][gt & 31] = hv;
            if (!LAST) out[((size_t)(b0 + bb) * TT + t) * HH + gt] = hv;
        }
        if constexpr (INK == 5) {
            if (tid < BB * 5 && t + 1 < TT) {
                int bb = tid / 5, k = tid % 5;
                s_x[nxt][bb][k] = xs1;
            }
        } else {
            if (tid < 64 && t + 1 < TT) {
                int row = tid >> 5, f = (tid & 31) * 4;
                *(float4*)&s_x[nxt][row][(f >> 5) * 36 + (f & 31)] = xs4;
            }
        }
        __syncthreads();
    }
    if (LAST) {
        if (tid < 128) {
            int bb = tid >> 6, l = tid & 63;
            float h0 = s_h[0][bb][l >> 5][l & 31];
            float h1 = s_h[0][bb][(l >> 5) + 2][l & 31];
            float s = h0 * fcw[l] + h1 * fcw[l + 64];
#pragma unroll
            for (int m = 32; m >= 1; m >>= 1) s += __shfl_xor(s, m, 64);
            if (l == 0) fcout[b0 + bb] = s + fcb[0];
        }
    }
}

extern "C" void kernel_launch(void* const* d_in, const int* in_sizes, int n_in,
                              void* d_out, int out_size, void* d_ws, size_t ws_size,
                              hipStream_t stream) {
    const float* x    = (const float*)d_in[0];
    const float* Wih0 = (const float*)d_in[1];
    const float* Whh0 = (const float*)d_in[2];
    const float* bih0 = (const float*)d_in[3];
    const float* bhh0 = (const float*)d_in[4];
    const float* WihR = (const float*)d_in[5];
    const float* WhhR = (const float*)d_in[6];
    const float* bihR = (const float*)d_in[7];
    const float* bhhR = (const float*)d_in[8];
    const float* fcw  = (const float*)d_in[9];
    const float* fcb  = (const float*)d_in[10];

    const size_t BUF_B = (size_t)BTOT * TT * HH * 4;   // 134,217,728
    const size_t XI_B  = (size_t)BTOT * TT * G3 * 4;   // 402,653,184
    float* buf = (float*)d_ws;

    if (ws_size >= BUF_B + XI_B) {
        float* xi = (float*)((char*)d_ws + BUF_B);
        const int GB = (BTOT * TT) / 32;   // 8192 GEMM blocks
        gru_rec<true, false><<<NBLK, NTHR, 0, stream>>>(x, buf, Wih0, Whh0, bih0, bhh0,
                                                        nullptr, nullptr, nullptr);
        for (int l = 0; l < 3; ++l) {
            xi_gemm<<<GB, 512, 0, stream>>>(buf, WihR + (size_t)l * G3 * HH, xi);
            if (l < 2)
                gru_rec<false, false><<<NBLK, NTHR, 0, stream>>>(
                    xi, buf, nullptr, WhhR + (size_t)l * G3 * HH, bihR + l * G3,
                    bhhR + l * G3, nullptr, nullptr, nullptr);
            else
                gru_rec<false, true><<<NBLK, NTHR, 0, stream>>>(
                    xi, buf, nullptr, WhhR + (size_t)l * G3 * HH, bihR + l * G3,
                    bhhR + l * G3, fcw, fcb, (float*)d_out);
        }
    } else {
        gru_fused<5, false><<<NBLK, NTHR, 0, stream>>>(x, buf, Wih0, Whh0, bih0, bhh0,
                                                       nullptr, nullptr, nullptr);
        gru_fused<128, false><<<NBLK, NTHR, 0, stream>>>(buf, buf, WihR, WhhR, bihR, bhhR,
                                                         nullptr, nullptr, nullptr);
        gru_fused<128, false><<<NBLK, NTHR, 0, stream>>>(buf, buf, WihR + G3 * HH,
                                                         WhhR + G3 * HH, bihR + G3,
                                                         bhhR + G3, nullptr, nullptr, nullptr);
        gru_fused<128, true><<<NBLK, NTHR, 0, stream>>>(buf, buf, WihR + 2 * G3 * HH,
                                                        WhhR + 2 * G3 * HH, bihR + 2 * G3,
                                                        bhhR + 2 * G3, fcw, fcb, (float*)d_out);
    }
}